// Round 7
// baseline (9368.951 us; speedup 1.0000x reference)
//
#include <hip/hip_runtime.h>
#include <hip/hip_bf16.h>
#include <math.h>

#define V 10000
#define E 512
#define H 1024
#define T 128
#define B 64
#define NWG 256
#define LDC 264   // LDS chunk row stride in ushorts (528 B, 16B-aligned rows)

typedef __bf16 bf16x8 __attribute__((ext_vector_type(8)));
typedef float f32x4 __attribute__((ext_vector_type(4)));
typedef unsigned short ushort8 __attribute__((ext_vector_type(8)));

// ---------------------------------------------------------------------------
// Cache-bypassing (coherent-at-MALL) access helpers (validated R4/R5).
// ---------------------------------------------------------------------------
__device__ __forceinline__ void store_f32_sc(float* p, float v) {
    asm volatile("global_store_dword %0, %1, off sc0 sc1" :: "v"(p), "v"(v) : "memory");
}
__device__ __forceinline__ int load_i32_sc(const int* p) {
    int r;
    asm volatile("global_load_dword %0, %1, off sc0 sc1\n\ts_waitcnt vmcnt(0)"
                 : "=v"(r) : "v"(p) : "memory");
    return r;
}

// ---------------------------------------------------------------------------
// Fence-free grid barrier: 8 striped counters (validated R4/R5).
// ---------------------------------------------------------------------------
__device__ __forceinline__ void gridbar(int* cnt, int gen) {
    asm volatile("s_waitcnt vmcnt(0)" ::: "memory");
    __syncthreads();
    if (threadIdx.x == 0)
        __hip_atomic_fetch_add(cnt + (blockIdx.x & 7) * 32, 1,
                               __ATOMIC_RELAXED, __HIP_MEMORY_SCOPE_AGENT);
    if (threadIdx.x < 8) {
        const int target = gen * (NWG / 8);
        while (load_i32_sc(cnt + threadIdx.x * 32) < target)
            __builtin_amdgcn_s_sleep(2);
    }
    __syncthreads();
}

// ---------------------------------------------------------------------------
// Split-pack 4 fp32 into truncated-hi bf16 and residual-lo bf16 (packed).
// ---------------------------------------------------------------------------
__device__ inline void splitpack(float4 v, uint2& hi, uint2& lo) {
    unsigned u0 = __float_as_uint(v.x), u1 = __float_as_uint(v.y);
    unsigned u2 = __float_as_uint(v.z), u3 = __float_as_uint(v.w);
    hi.x = __builtin_amdgcn_perm(u1, u0, 0x07060302u);
    hi.y = __builtin_amdgcn_perm(u3, u2, 0x07060302u);
    float l0 = v.x - __uint_as_float(u0 & 0xFFFF0000u);
    float l1 = v.y - __uint_as_float(u1 & 0xFFFF0000u);
    float l2 = v.z - __uint_as_float(u2 & 0xFFFF0000u);
    float l3 = v.w - __uint_as_float(u3 & 0xFFFF0000u);
    lo.x = __builtin_amdgcn_perm(__float_as_uint(l1), __float_as_uint(l0), 0x07060302u);
    lo.y = __builtin_amdgcn_perm(__float_as_uint(l3), __float_as_uint(l2), 0x07060302u);
}

__device__ __forceinline__ bf16x8 ld8(const unsigned short* p) {
    return __builtin_bit_cast(bf16x8, *(const ushort8*)p);
}
__device__ __forceinline__ f32x4 mfma3(f32x4 acc, bf16x8 ah, bf16x8 al,
                                       bf16x8 bh, bf16x8 bl) {
    acc = __builtin_amdgcn_mfma_f32_16x16x32_bf16(ah, bh, acc, 0, 0, 0);
    acc = __builtin_amdgcn_mfma_f32_16x16x32_bf16(al, bh, acc, 0, 0, 0);
    acc = __builtin_amdgcn_mfma_f32_16x16x32_bf16(ah, bl, acc, 0, 0, 0);
    return acc;
}

// ---------------------------------------------------------------------------
// Split-bf16 MFMA GEMM (proven R2-R5) — used only for the logits GEMM now.
// ---------------------------------------------------------------------------
__global__ __launch_bounds__(256) void gemm_mfma_split(
    const float* __restrict__ A, const float* __restrict__ W,
    const float* __restrict__ bias, float* __restrict__ C,
    int M, int N, int K, int lda, int ldbw, int ldc)
{
    __shared__ __align__(16) unsigned short Ah[128 * 40];
    __shared__ __align__(16) unsigned short Al[128 * 40];
    __shared__ __align__(16) unsigned short Bh[128 * 40];
    __shared__ __align__(16) unsigned short Bl[128 * 40];

    const int tid  = threadIdx.x;
    const int lane = tid & 63;
    const int wv   = tid >> 6;
    const int wm   = wv & 1, wn = wv >> 1;
    const int bn = blockIdx.x * 128;
    const int bm = blockIdx.y * 128;

    const float* apt[4];
    const float* bpt[4];
    bool bok[4];
    unsigned lofs[4];
    #pragma unroll
    for (int i = 0; i < 4; ++i) {
        int f4 = i * 256 + tid, r = f4 >> 3, kq = f4 & 7;
        apt[i] = A + (size_t)(bm + r) * lda + kq * 4;
        int gn = bn + r;
        bok[i] = (gn < N);
        bpt[i] = W + (size_t)(bok[i] ? gn : 0) * ldbw + kq * 4;
        lofs[i] = r * 40 + kq * 4;
    }

    f32x4 acc[4][4];
    #pragma unroll
    for (int i = 0; i < 4; ++i)
        #pragma unroll
        for (int j = 0; j < 4; ++j) acc[i][j] = (f32x4){0.f, 0.f, 0.f, 0.f};

    const int la  = lane & 15;
    const int kg8 = (lane >> 4) * 8;

    for (int k0 = 0; k0 < K; k0 += 32) {
        __syncthreads();
        #pragma unroll
        for (int i = 0; i < 4; ++i) {
            float4 va = *(const float4*)(apt[i] + k0);
            uint2 h, l;
            splitpack(va, h, l);
            *(uint2*)&Ah[lofs[i]] = h;
            *(uint2*)&Al[lofs[i]] = l;
            float4 vb = {0.f, 0.f, 0.f, 0.f};
            if (bok[i]) vb = *(const float4*)(bpt[i] + k0);
            splitpack(vb, h, l);
            *(uint2*)&Bh[lofs[i]] = h;
            *(uint2*)&Bl[lofs[i]] = l;
        }
        __syncthreads();

        bf16x8 ah[4], al[4];
        #pragma unroll
        for (int mt = 0; mt < 4; ++mt) {
            int row = (wm * 64 + mt * 16 + la) * 40 + kg8;
            ah[mt] = ld8(&Ah[row]);
            al[mt] = ld8(&Al[row]);
        }
        #pragma unroll
        for (int nt = 0; nt < 4; ++nt) {
            int row = (wn * 64 + nt * 16 + la) * 40 + kg8;
            bf16x8 bh = ld8(&Bh[row]);
            bf16x8 bl = ld8(&Bl[row]);
            #pragma unroll
            for (int mt = 0; mt < 4; ++mt)
                acc[mt][nt] = mfma3(acc[mt][nt], ah[mt], al[mt], bh, bl);
        }
    }

    #pragma unroll
    for (int mt = 0; mt < 4; ++mt) {
        int mrow = bm + wm * 64 + mt * 16 + (lane >> 4) * 4;
        #pragma unroll
        for (int nt = 0; nt < 4; ++nt) {
            int n = bn + wn * 64 + nt * 16 + la;
            if (n < N) {
                float bi = bias ? bias[n] : 0.f;
                #pragma unroll
                for (int r = 0; r < 4; ++r)
                    C[(size_t)(mrow + r) * ldc + n] = acc[mt][nt][r] + bi;
            }
        }
    }
}

// ---------------------------------------------------------------------------
// Prepass: split one fp32 matrix into bf16 hi/lo.
// ---------------------------------------------------------------------------
__global__ __launch_bounds__(256) void split_mat(
    const float* __restrict__ U, unsigned short* __restrict__ hi,
    unsigned short* __restrict__ lo, int nf4)
{
    int idx = blockIdx.x * 256 + threadIdx.x;
    if (idx >= nf4) return;
    float4 v = ((const float4*)U)[idx];
    uint2 h, l;
    splitpack(v, h, l);
    ((uint2*)hi)[idx] = h;
    ((uint2*)lo)[idx] = l;
}

// ---------------------------------------------------------------------------
// Fused 2-layer pipelined persistent GRU.
// Blocks 0-127: layer 0 (x = emb[tok[t]], K=512, W0 in-pipeline).
// Blocks 128-255: layer 1, one step behind (x = h0[t], K=1024, W1 in-pipeline).
// Per layer: 2 m-tiles (32 rows) x 64 col-slices (16 cols). Waves = (mh, kh).
// Phase A (p=2t[+2]): r,z gates + full Wx for own cols; rh -> sc stores;
//   z and Wx_h stay in registers (col-aligned partition).
// Phase B: h~ + update; h -> hRM (sc stores) and h_final at t=T-1.
// One gridbar per phase; 2T+2 = 258 phases total.
// ---------------------------------------------------------------------------
__global__ __launch_bounds__(256, 1) void gru_fused(
    const unsigned short* __restrict__ U0hi, const unsigned short* __restrict__ U0lo,
    const unsigned short* __restrict__ U1hi, const unsigned short* __restrict__ U1lo,
    const unsigned short* __restrict__ W0hi, const unsigned short* __restrict__ W0lo,
    const unsigned short* __restrict__ W1hi, const unsigned short* __restrict__ W1lo,
    const float* __restrict__ emb, const int* __restrict__ tok,
    const float* __restrict__ hidden,
    const float* __restrict__ br0, const float* __restrict__ bz0, const float* __restrict__ bh0,
    const float* __restrict__ br1, const float* __restrict__ bz1, const float* __restrict__ bh1,
    float* __restrict__ h0RM, float* __restrict__ rh0RM,
    float* __restrict__ h1RM, float* __restrict__ rh1RM,
    float* __restrict__ hfin, int* cnt)
{
    extern __shared__ char smem[];
    unsigned short* hs_hi = (unsigned short*)smem;          // 32*LDC
    unsigned short* hs_lo = hs_hi + 32 * LDC;
    unsigned short* xs_hi = hs_lo + 32 * LDC;
    unsigned short* xs_lo = xs_hi + 32 * LDC;
    f32x4* red = (f32x4*)(xs_lo + 32 * LDC);                // 2*5*64 f32x4

    const int tid  = threadIdx.x;
    const int lane = tid & 63;
    const int wv   = tid >> 6;
    const int mh   = wv & 1;
    const int kh   = wv >> 1;
    const int la   = lane & 15;
    const int kg8  = (lane >> 4) * 8;
    const int erow = (lane >> 4) * 4;
    const int trow = tid >> 3;      // staging row 0..31
    const int tq   = tid & 7;       // staging float4 col group

    const int bid   = blockIdx.x;
    const int layer = bid >> 7;
    const int lbid  = bid & 127;
    const int m0    = (lbid >> 6) * 32;
    const int j0    = (lbid & 63) * 16;

    const size_t HH = (size_t)H * H;
    const unsigned short* Uhi = layer ? U1hi : U0hi;
    const unsigned short* Ulo = layer ? U1lo : U0lo;
    const unsigned short* Whi = layer ? W1hi : W0hi;
    const unsigned short* Wlo = layer ? W1lo : W0lo;
    const int xK  = layer ? H : E;
    const int xch = xK / 256;                 // x K-chunks (4 or 2)
    float* hRM  = layer ? h1RM : h0RM;
    float* rhRM = layer ? rh1RM : rh0RM;
    const float* hinit = hidden + (size_t)layer * B * H;
    float* hfinl = hfin + (size_t)layer * B * H;
    const float bR = (layer ? br1 : br0)[j0 + la];
    const float bZ = (layer ? bz1 : bz0)[j0 + la];
    const float bH = (layer ? bh1 : bh0)[j0 + la];

    f32x4 zreg = (f32x4){0.f, 0.f, 0.f, 0.f};
    f32x4 wreg = (f32x4){0.f, 0.f, 0.f, 0.f};

    for (int p = 0; p < 2 * T + 2; ++p) {
        const int q = layer ? (p - 2) : p;
        if (q >= 0 && q < 2 * T) {
            const int t = q >> 1;
            const float* hprev = (t == 0) ? hinit : (hRM + (size_t)(t - 1) * B * H);
            const int rbase = m0 + mh * 16 + erow;

            if ((q & 1) == 0) {
                // ---------------- phase A: r, z, and Wx ----------------
                const float* xrp = layer
                    ? (h0RM + (size_t)t * B * H + (size_t)(m0 + trow) * H)
                    : (emb + (size_t)tok[t * B + m0 + trow] * E);
                const float* hrp = hprev + (size_t)(m0 + trow) * H;

                f32x4 aU0 = (f32x4){0.f,0.f,0.f,0.f}, aU1 = aU0;
                f32x4 aW0 = aU0, aW1 = aU0, aW2 = aU0;

                for (int kc = 0; kc < 4; ++kc) {
                    __syncthreads();
                    #pragma unroll
                    for (int i = 0; i < 8; ++i) {
                        float4 v = *(const float4*)(hrp + kc * 256 + (tq + i * 8) * 4);
                        uint2 h2, l2;
                        splitpack(v, h2, l2);
                        *(uint2*)&hs_hi[trow * LDC + (tq + i * 8) * 4] = h2;
                        *(uint2*)&hs_lo[trow * LDC + (tq + i * 8) * 4] = l2;
                    }
                    if (kc < xch) {
                        #pragma unroll
                        for (int i = 0; i < 8; ++i) {
                            float4 v = *(const float4*)(xrp + kc * 256 + (tq + i * 8) * 4);
                            uint2 h2, l2;
                            splitpack(v, h2, l2);
                            *(uint2*)&xs_hi[trow * LDC + (tq + i * 8) * 4] = h2;
                            *(uint2*)&xs_lo[trow * LDC + (tq + i * 8) * 4] = l2;
                        }
                    }
                    __syncthreads();
                    #pragma unroll
                    for (int ks = 0; ks < 4; ++ks) {
                        const int ko = kh * 128 + ks * 32 + kg8;
                        const int ar = (mh * 16 + la) * LDC + ko;
                        bf16x8 ah = ld8(&hs_hi[ar]);
                        bf16x8 al = ld8(&hs_lo[ar]);
                        const size_t ub = (size_t)(j0 + la) * H + kc * 256 + ko;
                        aU0 = mfma3(aU0, ah, al, ld8(Uhi + ub), ld8(Ulo + ub));
                        aU1 = mfma3(aU1, ah, al, ld8(Uhi + HH + ub), ld8(Ulo + HH + ub));
                        if (kc < xch) {
                            bf16x8 xh = ld8(&xs_hi[ar]);
                            bf16x8 xl = ld8(&xs_lo[ar]);
                            const size_t wb = (size_t)(j0 + la) * xK + kc * 256 + ko;
                            const size_t gs = (size_t)H * xK;
                            aW0 = mfma3(aW0, xh, xl, ld8(Whi + wb), ld8(Wlo + wb));
                            aW1 = mfma3(aW1, xh, xl, ld8(Whi + gs + wb), ld8(Wlo + gs + wb));
                            aW2 = mfma3(aW2, xh, xl, ld8(Whi + 2 * gs + wb), ld8(Wlo + 2 * gs + wb));
                        }
                    }
                }
                if (kh == 1) {
                    red[(mh * 5 + 0) * 64 + lane] = aW0;
                    red[(mh * 5 + 1) * 64 + lane] = aW1;
                    red[(mh * 5 + 2) * 64 + lane] = aW2;
                    red[(mh * 5 + 3) * 64 + lane] = aU0;
                    red[(mh * 5 + 4) * 64 + lane] = aU1;
                }
                __syncthreads();
                if (kh == 0) {
                    aW0 += red[(mh * 5 + 0) * 64 + lane];
                    aW1 += red[(mh * 5 + 1) * 64 + lane];
                    aW2 += red[(mh * 5 + 2) * 64 + lane];
                    aU0 += red[(mh * 5 + 3) * 64 + lane];
                    aU1 += red[(mh * 5 + 4) * 64 + lane];
                    #pragma unroll
                    for (int qq = 0; qq < 4; ++qq) {
                        float hv = hprev[(size_t)(rbase + qq) * H + j0 + la];
                        float rg = 1.f / (1.f + __expf(-(aU0[qq] + aW0[qq] + bR)));
                        zreg[qq] = 1.f / (1.f + __expf(-(aU1[qq] + aW1[qq] + bZ)));
                        wreg[qq] = aW2[qq] + bH;
                        store_f32_sc(rhRM + (size_t)t * B * H + (size_t)(rbase + qq) * H + j0 + la,
                                     rg * hv);
                    }
                }
            } else {
                // ---------------- phase B: h~ and update ----------------
                const float* rrp = rhRM + (size_t)t * B * H + (size_t)(m0 + trow) * H;
                f32x4 aU = (f32x4){0.f, 0.f, 0.f, 0.f};
                for (int kc = 0; kc < 4; ++kc) {
                    __syncthreads();
                    #pragma unroll
                    for (int i = 0; i < 8; ++i) {
                        float4 v = *(const float4*)(rrp + kc * 256 + (tq + i * 8) * 4);
                        uint2 h2, l2;
                        splitpack(v, h2, l2);
                        *(uint2*)&hs_hi[trow * LDC + (tq + i * 8) * 4] = h2;
                        *(uint2*)&hs_lo[trow * LDC + (tq + i * 8) * 4] = l2;
                    }
                    __syncthreads();
                    #pragma unroll
                    for (int ks = 0; ks < 4; ++ks) {
                        const int ko = kh * 128 + ks * 32 + kg8;
                        const int ar = (mh * 16 + la) * LDC + ko;
                        const size_t ub = (size_t)(j0 + la) * H + kc * 256 + ko;
                        aU = mfma3(aU, ld8(&hs_hi[ar]), ld8(&hs_lo[ar]),
                                   ld8(Uhi + 2 * HH + ub), ld8(Ulo + 2 * HH + ub));
                    }
                }
                if (kh == 1) red[(mh * 5) * 64 + lane] = aU;
                __syncthreads();
                if (kh == 0) {
                    aU += red[(mh * 5) * 64 + lane];
                    #pragma unroll
                    for (int qq = 0; qq < 4; ++qq) {
                        float ht = tanhf(aU[qq] + wreg[qq]);
                        float hold = hprev[(size_t)(rbase + qq) * H + j0 + la];
                        float hn = (1.f - zreg[qq]) * hold + zreg[qq] * ht;
                        store_f32_sc(hRM + (size_t)t * B * H + (size_t)(rbase + qq) * H + j0 + la, hn);
                        if (t == T - 1)
                            store_f32_sc(hfinl + (size_t)(rbase + qq) * H + j0 + la, hn);
                    }
                }
            }
        }
        gridbar(cnt, p + 1);
    }
}

// ---------------------------------------------------------------------------
extern "C" void kernel_launch(void* const* d_in, const int* in_sizes, int n_in,
                              void* d_out, int out_size, void* d_ws, size_t ws_size,
                              hipStream_t stream)
{
    const int*   tok    = (const int*)d_in[0];
    const float* hidden = (const float*)d_in[1];
    const float* emb    = (const float*)d_in[2];
    const float* Wr0 = (const float*)d_in[3],  *br0 = (const float*)d_in[4];
    const float* Wz0 = (const float*)d_in[5],  *bz0 = (const float*)d_in[6];
    const float* Wh0 = (const float*)d_in[7],  *bh0 = (const float*)d_in[8];
    const float* Ur0 = (const float*)d_in[9],  *Uz0 = (const float*)d_in[10], *Uh0 = (const float*)d_in[11];
    const float* Wr1 = (const float*)d_in[12], *br1 = (const float*)d_in[13];
    const float* Wz1 = (const float*)d_in[14], *bz1 = (const float*)d_in[15];
    const float* Wh1 = (const float*)d_in[16], *bh1 = (const float*)d_in[17];
    const float* Ur1 = (const float*)d_in[18], *Uz1 = (const float*)d_in[19], *Uh1 = (const float*)d_in[20];
    const float* Wout = (const float*)d_in[21], *bout = (const float*)d_in[22];
    float* out = (float*)d_out;

    const size_t HH = (size_t)H * H;
    const size_t HE = (size_t)H * E;

    float* ws    = (float*)d_ws;
    float* h0RM  = ws;                                   // T*B*H
    float* rh0RM = h0RM  + (size_t)T * B * H;
    float* h1RM  = rh0RM + (size_t)T * B * H;
    float* rh1RM = h1RM  + (size_t)T * B * H;
    unsigned short* U0hi = (unsigned short*)(rh1RM + (size_t)T * B * H);
    unsigned short* U0lo = U0hi + 3 * HH;
    unsigned short* U1hi = U0lo + 3 * HH;
    unsigned short* U1lo = U1hi + 3 * HH;
    unsigned short* W1hi = U1lo + 3 * HH;
    unsigned short* W1lo = W1hi + 3 * HH;
    unsigned short* W0hi = W1lo + 3 * HH;
    unsigned short* W0lo = W0hi + 3 * HE;
    int* cnt = (int*)(W0lo + 3 * HE);

    static bool attr_set = false;
    if (!attr_set) {
        (void)hipFuncSetAttribute((const void*)gru_fused,
                                  hipFuncAttributeMaxDynamicSharedMemorySize, 77824);
        attr_set = true;
    }

    (void)hipMemsetAsync(cnt, 0, 256 * sizeof(int), stream);

    const int nHH = (int)(HH / 4), nHE = (int)(HE / 4);
    split_mat<<<nHH / 256, 256, 0, stream>>>(Ur0, U0hi + 0 * HH, U0lo + 0 * HH, nHH);
    split_mat<<<nHH / 256, 256, 0, stream>>>(Uz0, U0hi + 1 * HH, U0lo + 1 * HH, nHH);
    split_mat<<<nHH / 256, 256, 0, stream>>>(Uh0, U0hi + 2 * HH, U0lo + 2 * HH, nHH);
    split_mat<<<nHH / 256, 256, 0, stream>>>(Ur1, U1hi + 0 * HH, U1lo + 0 * HH, nHH);
    split_mat<<<nHH / 256, 256, 0, stream>>>(Uz1, U1hi + 1 * HH, U1lo + 1 * HH, nHH);
    split_mat<<<nHH / 256, 256, 0, stream>>>(Uh1, U1hi + 2 * HH, U1lo + 2 * HH, nHH);
    split_mat<<<nHH / 256, 256, 0, stream>>>(Wr1, W1hi + 0 * HH, W1lo + 0 * HH, nHH);
    split_mat<<<nHH / 256, 256, 0, stream>>>(Wz1, W1hi + 1 * HH, W1lo + 1 * HH, nHH);
    split_mat<<<nHH / 256, 256, 0, stream>>>(Wh1, W1hi + 2 * HH, W1lo + 2 * HH, nHH);
    split_mat<<<nHE / 256, 256, 0, stream>>>(Wr0, W0hi + 0 * HE, W0lo + 0 * HE, nHE);
    split_mat<<<nHE / 256, 256, 0, stream>>>(Wz0, W0hi + 1 * HE, W0lo + 1 * HE, nHE);
    split_mat<<<nHE / 256, 256, 0, stream>>>(Wh0, W0hi + 2 * HE, W0lo + 2 * HE, nHE);

    gru_fused<<<NWG, 256, 77824, stream>>>(
        U0hi, U0lo, U1hi, U1lo, W0hi, W0lo, W1hi, W1lo,
        emb, tok, hidden, br0, bz0, bh0, br1, bz1, bh1,
        h0RM, rh0RM, h1RM, rh1RM, out + (size_t)T * B * V, cnt);

    // logits = h1_seq @ Wout^T + bout
    gemm_mfma_split<<<dim3((V + 127) / 128, T * B / 128), 256, 0, stream>>>(
        h1RM, Wout, bout, out, T * B, V, H, H, H, V);
}

// Round 8
// 6873.935 us; speedup vs baseline: 1.3630x; 1.3630x over previous
//
#include <hip/hip_runtime.h>
#include <hip/hip_bf16.h>
#include <math.h>

#define V 10000
#define E 512
#define H 1024
#define T 128
#define B 64
#define NWG 256
#define LDC 264   // LDS chunk row stride in ushorts (528 B; 16B-slot stride 33 = odd)

typedef __bf16 bf16x8 __attribute__((ext_vector_type(8)));
typedef float f32x4 __attribute__((ext_vector_type(4)));
typedef unsigned short ushort8 __attribute__((ext_vector_type(8)));

// ---------------------------------------------------------------------------
// Cache-bypassing (coherent-at-MALL) access helpers (validated R4-R7).
// ---------------------------------------------------------------------------
__device__ __forceinline__ void store_f32_sc(float* p, float v) {
    asm volatile("global_store_dword %0, %1, off sc0 sc1" :: "v"(p), "v"(v) : "memory");
}
__device__ __forceinline__ int load_i32_sc(const int* p) {
    int r;
    asm volatile("global_load_dword %0, %1, off sc0 sc1\n\ts_waitcnt vmcnt(0)"
                 : "=v"(r) : "v"(p) : "memory");
    return r;
}

// ---------------------------------------------------------------------------
// Fence-free grid barrier: 8 striped counters (validated R4-R7).
// ---------------------------------------------------------------------------
__device__ __forceinline__ void gridbar(int* cnt, int gen) {
    asm volatile("s_waitcnt vmcnt(0)" ::: "memory");
    __syncthreads();
    if (threadIdx.x == 0)
        __hip_atomic_fetch_add(cnt + (blockIdx.x & 7) * 32, 1,
                               __ATOMIC_RELAXED, __HIP_MEMORY_SCOPE_AGENT);
    if (threadIdx.x < 8) {
        const int target = gen * (NWG / 8);
        while (load_i32_sc(cnt + threadIdx.x * 32) < target)
            __builtin_amdgcn_s_sleep(2);
    }
    __syncthreads();
}

// ---------------------------------------------------------------------------
// Split-pack 4 fp32 into truncated-hi bf16 and residual-lo bf16 (packed).
// ---------------------------------------------------------------------------
__device__ inline void splitpack(float4 v, uint2& hi, uint2& lo) {
    unsigned u0 = __float_as_uint(v.x), u1 = __float_as_uint(v.y);
    unsigned u2 = __float_as_uint(v.z), u3 = __float_as_uint(v.w);
    hi.x = __builtin_amdgcn_perm(u1, u0, 0x07060302u);
    hi.y = __builtin_amdgcn_perm(u3, u2, 0x07060302u);
    float l0 = v.x - __uint_as_float(u0 & 0xFFFF0000u);
    float l1 = v.y - __uint_as_float(u1 & 0xFFFF0000u);
    float l2 = v.z - __uint_as_float(u2 & 0xFFFF0000u);
    float l3 = v.w - __uint_as_float(u3 & 0xFFFF0000u);
    lo.x = __builtin_amdgcn_perm(__float_as_uint(l1), __float_as_uint(l0), 0x07060302u);
    lo.y = __builtin_amdgcn_perm(__float_as_uint(l3), __float_as_uint(l2), 0x07060302u);
}

__device__ __forceinline__ bf16x8 ld8(const unsigned short* p) {
    return __builtin_bit_cast(bf16x8, *(const ushort8*)p);
}
__device__ __forceinline__ f32x4 mfma3(f32x4 acc, bf16x8 ah, bf16x8 al,
                                       bf16x8 bh, bf16x8 bl) {
    acc = __builtin_amdgcn_mfma_f32_16x16x32_bf16(ah, bh, acc, 0, 0, 0);
    acc = __builtin_amdgcn_mfma_f32_16x16x32_bf16(al, bh, acc, 0, 0, 0);
    acc = __builtin_amdgcn_mfma_f32_16x16x32_bf16(ah, bl, acc, 0, 0, 0);
    return acc;
}

// ---------------------------------------------------------------------------
// Split-bf16 MFMA GEMM with optional row gather + column offset (R5 version).
// ---------------------------------------------------------------------------
__global__ __launch_bounds__(256) void gemm_mfma_split(
    const float* __restrict__ A, const float* __restrict__ W,
    const float* __restrict__ bias, float* __restrict__ C,
    const int* __restrict__ rowidx,
    int M, int N, int K, int lda, int ldbw, int ldc, int coff)
{
    __shared__ __align__(16) unsigned short Ah[128 * 40];
    __shared__ __align__(16) unsigned short Al[128 * 40];
    __shared__ __align__(16) unsigned short Bh[128 * 40];
    __shared__ __align__(16) unsigned short Bl[128 * 40];

    const int tid  = threadIdx.x;
    const int lane = tid & 63;
    const int wv   = tid >> 6;
    const int wm   = wv & 1, wn = wv >> 1;
    const int bn = blockIdx.x * 128;
    const int bm = blockIdx.y * 128;

    const float* apt[4];
    const float* bpt[4];
    bool bok[4];
    unsigned lofs[4];
    #pragma unroll
    for (int i = 0; i < 4; ++i) {
        int f4 = i * 256 + tid, r = f4 >> 3, kq = f4 & 7;
        int gm = bm + r;
        int ar = rowidx ? rowidx[gm] : gm;
        apt[i] = A + (size_t)ar * lda + kq * 4;
        int gn = bn + r;
        bok[i] = (gn < N);
        bpt[i] = W + (size_t)(bok[i] ? gn : 0) * ldbw + kq * 4;
        lofs[i] = r * 40 + kq * 4;
    }

    f32x4 acc[4][4];
    #pragma unroll
    for (int i = 0; i < 4; ++i)
        #pragma unroll
        for (int j = 0; j < 4; ++j) acc[i][j] = (f32x4){0.f, 0.f, 0.f, 0.f};

    const int la  = lane & 15;
    const int kg8 = (lane >> 4) * 8;

    for (int k0 = 0; k0 < K; k0 += 32) {
        __syncthreads();
        #pragma unroll
        for (int i = 0; i < 4; ++i) {
            float4 va = *(const float4*)(apt[i] + k0);
            uint2 h, l;
            splitpack(va, h, l);
            *(uint2*)&Ah[lofs[i]] = h;
            *(uint2*)&Al[lofs[i]] = l;
            float4 vb = {0.f, 0.f, 0.f, 0.f};
            if (bok[i]) vb = *(const float4*)(bpt[i] + k0);
            splitpack(vb, h, l);
            *(uint2*)&Bh[lofs[i]] = h;
            *(uint2*)&Bl[lofs[i]] = l;
        }
        __syncthreads();

        bf16x8 ah[4], al[4];
        #pragma unroll
        for (int mt = 0; mt < 4; ++mt) {
            int row = (wm * 64 + mt * 16 + la) * 40 + kg8;
            ah[mt] = ld8(&Ah[row]);
            al[mt] = ld8(&Al[row]);
        }
        #pragma unroll
        for (int nt = 0; nt < 4; ++nt) {
            int row = (wn * 64 + nt * 16 + la) * 40 + kg8;
            bf16x8 bh = ld8(&Bh[row]);
            bf16x8 bl = ld8(&Bl[row]);
            #pragma unroll
            for (int mt = 0; mt < 4; ++mt)
                acc[mt][nt] = mfma3(acc[mt][nt], ah[mt], al[mt], bh, bl);
        }
    }

    #pragma unroll
    for (int mt = 0; mt < 4; ++mt) {
        int mrow = bm + wm * 64 + mt * 16 + (lane >> 4) * 4;
        #pragma unroll
        for (int nt = 0; nt < 4; ++nt) {
            int n = bn + wn * 64 + nt * 16 + la;
            if (n < N) {
                float bi = bias ? bias[n] : 0.f;
                #pragma unroll
                for (int r = 0; r < 4; ++r)
                    C[(size_t)(mrow + r) * ldc + n + coff] = acc[mt][nt][r] + bi;
            }
        }
    }
}

// ---------------------------------------------------------------------------
// Prepass: split one fp32 matrix into bf16 hi/lo.
// ---------------------------------------------------------------------------
__global__ __launch_bounds__(256) void split_mat(
    const float* __restrict__ U, unsigned short* __restrict__ hi,
    unsigned short* __restrict__ lo, int nf4)
{
    int idx = blockIdx.x * 256 + threadIdx.x;
    if (idx >= nf4) return;
    float4 v = ((const float4*)U)[idx];
    uint2 h, l;
    splitpack(v, h, l);
    ((uint2*)hi)[idx] = h;
    ((uint2*)lo)[idx] = l;
}

// ---------------------------------------------------------------------------
// Fused 2-layer pipelined persistent GRU with XCD-resident weights.
// Block decode: xcd = bid & 7; sub = bid >> 3; layer = sub & 1;
//   m0 = ((sub>>1) & 1) * 32; col-slice j0 = (xcd*8 + (sub>>2)) * 16.
// => XCD x owns output cols [x*128, x*128+128) of U0, U1 AND W1: its 32
//    blocks (2 layers x 2 m-tiles x 8 slices) are the only readers of those
//    weight slices -> ~4.5 MB persistent L2 set per XCD.
// L0: Wx0 precomputed (bias folded). L1: W1x computed in-pipeline (x = h0[t]).
// Phase A: r,z (+W1x for L1); rh -> sc stores; z, wx_h in registers.
// Phase B: h~ + update; h -> hRM; h_final at t = T-1. 2T+2 = 258 rounds.
// ---------------------------------------------------------------------------
__global__ __launch_bounds__(256, 1) void gru_fused(
    const unsigned short* __restrict__ U0hi, const unsigned short* __restrict__ U0lo,
    const unsigned short* __restrict__ U1hi, const unsigned short* __restrict__ U1lo,
    const unsigned short* __restrict__ W1hi, const unsigned short* __restrict__ W1lo,
    const float* __restrict__ Wx0, const float* __restrict__ hidden,
    const float* __restrict__ br1, const float* __restrict__ bz1, const float* __restrict__ bh1,
    float* __restrict__ h0RM, float* __restrict__ rh0RM,
    float* __restrict__ h1RM, float* __restrict__ rh1RM,
    float* __restrict__ hfin, int* cnt)
{
    extern __shared__ char smem[];
    unsigned short* hs_hi = (unsigned short*)smem;          // 32*LDC
    unsigned short* hs_lo = hs_hi + 32 * LDC;
    unsigned short* xs_hi = hs_lo + 32 * LDC;
    unsigned short* xs_lo = xs_hi + 32 * LDC;
    f32x4* red = (f32x4*)(xs_lo + 32 * LDC);                // 2*5*64 f32x4

    const int tid  = threadIdx.x;
    const int lane = tid & 63;
    const int wv   = tid >> 6;
    const int mh   = wv & 1;
    const int kh   = wv >> 1;
    const int la   = lane & 15;
    const int kg8  = (lane >> 4) * 8;
    const int erow = (lane >> 4) * 4;
    const int trow = tid >> 3;      // staging row 0..31
    const int tq   = tid & 7;       // staging float4 col group

    const int bid   = blockIdx.x;
    const int xcd   = bid & 7;
    const int sub   = bid >> 3;
    const int layer = sub & 1;
    const int m0    = ((sub >> 1) & 1) * 32;
    const int j0    = (xcd * 8 + (sub >> 2)) * 16;

    const size_t HH = (size_t)H * H;
    const unsigned short* Uhi = layer ? U1hi : U0hi;
    const unsigned short* Ulo = layer ? U1lo : U0lo;
    float* hRM  = layer ? h1RM : h0RM;
    float* rhRM = layer ? rh1RM : rh0RM;
    const float* hinit = hidden + (size_t)layer * B * H;
    float* hfinl = hfin + (size_t)layer * B * H;
    const float bR = layer ? br1[j0 + la] : 0.f;
    const float bZ = layer ? bz1[j0 + la] : 0.f;
    const float bH = layer ? bh1[j0 + la] : 0.f;

    f32x4 zreg = (f32x4){0.f, 0.f, 0.f, 0.f};
    f32x4 wreg = (f32x4){0.f, 0.f, 0.f, 0.f};

    for (int p = 0; p < 2 * T + 2; ++p) {
        const int q = layer ? (p - 2) : p;
        if (q >= 0 && q < 2 * T) {
            const int t = q >> 1;
            const float* hprev = (t == 0) ? hinit : (hRM + (size_t)(t - 1) * B * H);
            const int rbase = m0 + mh * 16 + erow;

            if ((q & 1) == 0) {
                // ---------------- phase A: r, z (+ W1x for L1) ----------------
                const float* hrp = hprev + (size_t)(m0 + trow) * H;
                const float* xrp = h0RM + (size_t)t * B * H + (size_t)(m0 + trow) * H;

                f32x4 aU0 = (f32x4){0.f,0.f,0.f,0.f}, aU1 = aU0;
                f32x4 aW0 = aU0, aW1 = aU0, aW2 = aU0;

                for (int kc = 0; kc < 4; ++kc) {
                    __syncthreads();
                    #pragma unroll
                    for (int i = 0; i < 8; ++i) {
                        float4 v = *(const float4*)(hrp + kc * 256 + (tq + i * 8) * 4);
                        uint2 h2, l2;
                        splitpack(v, h2, l2);
                        *(uint2*)&hs_hi[trow * LDC + (tq + i * 8) * 4] = h2;
                        *(uint2*)&hs_lo[trow * LDC + (tq + i * 8) * 4] = l2;
                    }
                    if (layer) {
                        #pragma unroll
                        for (int i = 0; i < 8; ++i) {
                            float4 v = *(const float4*)(xrp + kc * 256 + (tq + i * 8) * 4);
                            uint2 h2, l2;
                            splitpack(v, h2, l2);
                            *(uint2*)&xs_hi[trow * LDC + (tq + i * 8) * 4] = h2;
                            *(uint2*)&xs_lo[trow * LDC + (tq + i * 8) * 4] = l2;
                        }
                    }
                    __syncthreads();
                    #pragma unroll
                    for (int ks = 0; ks < 4; ++ks) {
                        const int ko = kh * 128 + ks * 32 + kg8;
                        const int ar = (mh * 16 + la) * LDC + ko;
                        bf16x8 ah = ld8(&hs_hi[ar]);
                        bf16x8 al = ld8(&hs_lo[ar]);
                        const size_t ub = (size_t)(j0 + la) * H + kc * 256 + ko;
                        aU0 = mfma3(aU0, ah, al, ld8(Uhi + ub), ld8(Ulo + ub));
                        aU1 = mfma3(aU1, ah, al, ld8(Uhi + HH + ub), ld8(Ulo + HH + ub));
                        if (layer) {
                            bf16x8 xh = ld8(&xs_hi[ar]);
                            bf16x8 xl = ld8(&xs_lo[ar]);
                            aW0 = mfma3(aW0, xh, xl, ld8(W1hi + ub), ld8(W1lo + ub));
                            aW1 = mfma3(aW1, xh, xl, ld8(W1hi + HH + ub), ld8(W1lo + HH + ub));
                            aW2 = mfma3(aW2, xh, xl, ld8(W1hi + 2 * HH + ub), ld8(W1lo + 2 * HH + ub));
                        }
                    }
                }
                if (kh == 1) {
                    red[(mh * 5 + 0) * 64 + lane] = aU0;
                    red[(mh * 5 + 1) * 64 + lane] = aU1;
                    if (layer) {
                        red[(mh * 5 + 2) * 64 + lane] = aW0;
                        red[(mh * 5 + 3) * 64 + lane] = aW1;
                        red[(mh * 5 + 4) * 64 + lane] = aW2;
                    }
                }
                __syncthreads();
                if (kh == 0) {
                    aU0 += red[(mh * 5 + 0) * 64 + lane];
                    aU1 += red[(mh * 5 + 1) * 64 + lane];
                    if (layer) {
                        aW0 += red[(mh * 5 + 2) * 64 + lane];
                        aW1 += red[(mh * 5 + 3) * 64 + lane];
                        aW2 += red[(mh * 5 + 4) * 64 + lane];
                    }
                    #pragma unroll
                    for (int qq = 0; qq < 4; ++qq) {
                        float wr, wz, wh;
                        if (layer) {
                            wr = aW0[qq] + bR; wz = aW1[qq] + bZ; wh = aW2[qq] + bH;
                        } else {
                            const float* wxr = Wx0 + ((size_t)t * B + rbase + qq) * (3 * H) + j0 + la;
                            wr = wxr[0]; wz = wxr[H]; wh = wxr[2 * H];
                        }
                        float hv = hprev[(size_t)(rbase + qq) * H + j0 + la];
                        float rg = 1.f / (1.f + __expf(-(aU0[qq] + wr)));
                        zreg[qq] = 1.f / (1.f + __expf(-(aU1[qq] + wz)));
                        wreg[qq] = wh;
                        store_f32_sc(rhRM + (size_t)t * B * H + (size_t)(rbase + qq) * H + j0 + la,
                                     rg * hv);
                    }
                }
            } else {
                // ---------------- phase B: h~ and update ----------------
                const float* rrp = rhRM + (size_t)t * B * H + (size_t)(m0 + trow) * H;
                f32x4 aU = (f32x4){0.f, 0.f, 0.f, 0.f};
                for (int kc = 0; kc < 4; ++kc) {
                    __syncthreads();
                    #pragma unroll
                    for (int i = 0; i < 8; ++i) {
                        float4 v = *(const float4*)(rrp + kc * 256 + (tq + i * 8) * 4);
                        uint2 h2, l2;
                        splitpack(v, h2, l2);
                        *(uint2*)&hs_hi[trow * LDC + (tq + i * 8) * 4] = h2;
                        *(uint2*)&hs_lo[trow * LDC + (tq + i * 8) * 4] = l2;
                    }
                    __syncthreads();
                    #pragma unroll
                    for (int ks = 0; ks < 4; ++ks) {
                        const int ko = kh * 128 + ks * 32 + kg8;
                        const int ar = (mh * 16 + la) * LDC + ko;
                        const size_t ub = (size_t)(j0 + la) * H + kc * 256 + ko;
                        aU = mfma3(aU, ld8(&hs_hi[ar]), ld8(&hs_lo[ar]),
                                   ld8(Uhi + 2 * HH + ub), ld8(Ulo + 2 * HH + ub));
                    }
                }
                if (kh == 1) red[(mh * 5) * 64 + lane] = aU;
                __syncthreads();
                if (kh == 0) {
                    aU += red[(mh * 5) * 64 + lane];
                    #pragma unroll
                    for (int qq = 0; qq < 4; ++qq) {
                        float ht = tanhf(aU[qq] + wreg[qq]);
                        float hold = hprev[(size_t)(rbase + qq) * H + j0 + la];
                        float hn = (1.f - zreg[qq]) * hold + zreg[qq] * ht;
                        store_f32_sc(hRM + (size_t)t * B * H + (size_t)(rbase + qq) * H + j0 + la, hn);
                        if (t == T - 1)
                            store_f32_sc(hfinl + (size_t)(rbase + qq) * H + j0 + la, hn);
                    }
                }
            }
        }
        gridbar(cnt, p + 1);
    }
}

// ---------------------------------------------------------------------------
extern "C" void kernel_launch(void* const* d_in, const int* in_sizes, int n_in,
                              void* d_out, int out_size, void* d_ws, size_t ws_size,
                              hipStream_t stream)
{
    const int*   tok    = (const int*)d_in[0];
    const float* hidden = (const float*)d_in[1];
    const float* emb    = (const float*)d_in[2];
    const float* Wr0 = (const float*)d_in[3],  *br0 = (const float*)d_in[4];
    const float* Wz0 = (const float*)d_in[5],  *bz0 = (const float*)d_in[6];
    const float* Wh0 = (const float*)d_in[7],  *bh0 = (const float*)d_in[8];
    const float* Ur0 = (const float*)d_in[9],  *Uz0 = (const float*)d_in[10], *Uh0 = (const float*)d_in[11];
    const float* Wr1 = (const float*)d_in[12], *br1 = (const float*)d_in[13];
    const float* Wz1 = (const float*)d_in[14], *bz1 = (const float*)d_in[15];
    const float* Wh1 = (const float*)d_in[16], *bh1 = (const float*)d_in[17];
    const float* Ur1 = (const float*)d_in[18], *Uz1 = (const float*)d_in[19], *Uh1 = (const float*)d_in[20];
    const float* Wout = (const float*)d_in[21], *bout = (const float*)d_in[22];
    float* out = (float*)d_out;

    const size_t HH = (size_t)H * H;

    float* ws    = (float*)d_ws;
    float* Wx0   = ws;                                   // T*B*3H
    float* h0RM  = Wx0   + (size_t)T * B * 3 * H;        // T*B*H
    float* rh0RM = h0RM  + (size_t)T * B * H;
    float* h1RM  = rh0RM + (size_t)T * B * H;
    float* rh1RM = h1RM  + (size_t)T * B * H;
    unsigned short* U0hi = (unsigned short*)(rh1RM + (size_t)T * B * H);
    unsigned short* U0lo = U0hi + 3 * HH;
    unsigned short* U1hi = U0lo + 3 * HH;
    unsigned short* U1lo = U1hi + 3 * HH;
    unsigned short* W1hi = U1lo + 3 * HH;
    unsigned short* W1lo = W1hi + 3 * HH;
    int* cnt = (int*)(W1lo + 3 * HH);

    static bool attr_set = false;
    if (!attr_set) {
        (void)hipFuncSetAttribute((const void*)gru_fused,
                                  hipFuncAttributeMaxDynamicSharedMemorySize, 77824);
        attr_set = true;
    }

    (void)hipMemsetAsync(cnt, 0, 256 * sizeof(int), stream);

    const int nHH = (int)(HH / 4);
    split_mat<<<nHH / 256, 256, 0, stream>>>(Ur0, U0hi + 0 * HH, U0lo + 0 * HH, nHH);
    split_mat<<<nHH / 256, 256, 0, stream>>>(Uz0, U0hi + 1 * HH, U0lo + 1 * HH, nHH);
    split_mat<<<nHH / 256, 256, 0, stream>>>(Uh0, U0hi + 2 * HH, U0lo + 2 * HH, nHH);
    split_mat<<<nHH / 256, 256, 0, stream>>>(Ur1, U1hi + 0 * HH, U1lo + 0 * HH, nHH);
    split_mat<<<nHH / 256, 256, 0, stream>>>(Uz1, U1hi + 1 * HH, U1lo + 1 * HH, nHH);
    split_mat<<<nHH / 256, 256, 0, stream>>>(Uh1, U1hi + 2 * HH, U1lo + 2 * HH, nHH);
    split_mat<<<nHH / 256, 256, 0, stream>>>(Wr1, W1hi + 0 * HH, W1lo + 0 * HH, nHH);
    split_mat<<<nHH / 256, 256, 0, stream>>>(Wz1, W1hi + 1 * HH, W1lo + 1 * HH, nHH);
    split_mat<<<nHH / 256, 256, 0, stream>>>(Wh1, W1hi + 2 * HH, W1lo + 2 * HH, nHH);

    // ---- Wx0 = emb[tok] @ [Wr0;Wz0;Wh0]^T + b (gather fused, bias folded)
    gemm_mfma_split<<<dim3(H / 128, T * B / 128), 256, 0, stream>>>(emb, Wr0, br0, Wx0, tok, T * B, H, E, E, E, 3 * H, 0);
    gemm_mfma_split<<<dim3(H / 128, T * B / 128), 256, 0, stream>>>(emb, Wz0, bz0, Wx0, tok, T * B, H, E, E, E, 3 * H, H);
    gemm_mfma_split<<<dim3(H / 128, T * B / 128), 256, 0, stream>>>(emb, Wh0, bh0, Wx0, tok, T * B, H, E, E, E, 3 * H, 2 * H);

    gru_fused<<<NWG, 256, 77824, stream>>>(
        U0hi, U0lo, U1hi, U1lo, W1hi, W1lo,
        Wx0, hidden, br1, bz1, bh1,
        h0RM, rh0RM, h1RM, rh1RM, out + (size_t)T * B * V, cnt);

    // logits = h1_seq @ Wout^T + bout
    gemm_mfma_split<<<dim3((V + 127) / 128, T * B / 128), 256, 0, stream>>>(
        h1RM, Wout, bout, out, nullptr, T * B, V, H, H, H, V, 0);
}

// Round 10
// 5547.824 us; speedup vs baseline: 1.6888x; 1.2390x over previous
//
#include <hip/hip_runtime.h>
#include <hip/hip_bf16.h>
#include <math.h>

#define V 10000
#define E 512
#define H 1024
#define T 128
#define B 64
#define NWG 256
#define LDK 1032   // LDS row stride in ushorts (2064 B -> 2-way bank aliasing, free)

typedef __bf16 bf16x8 __attribute__((ext_vector_type(8)));
typedef float f32x4 __attribute__((ext_vector_type(4)));
typedef unsigned short ushort8 __attribute__((ext_vector_type(8)));

// ---------------------------------------------------------------------------
// Cache-bypassing (coherent-at-MALL) access helpers (validated R4-R8).
// ---------------------------------------------------------------------------
__device__ __forceinline__ void store_f32_sc(float* p, float v) {
    asm volatile("global_store_dword %0, %1, off sc0 sc1" :: "v"(p), "v"(v) : "memory");
}
__device__ __forceinline__ int load_i32_sc(const int* p) {
    int r;
    asm volatile("global_load_dword %0, %1, off sc0 sc1\n\ts_waitcnt vmcnt(0)"
                 : "=v"(r) : "v"(p) : "memory");
    return r;
}

// ---------------------------------------------------------------------------
// Fence-free grid barrier: 8 striped counters (validated R4-R8).
// ---------------------------------------------------------------------------
__device__ __forceinline__ void gridbar(int* cnt, int gen) {
    asm volatile("s_waitcnt vmcnt(0)" ::: "memory");
    __syncthreads();
    if (threadIdx.x == 0)
        __hip_atomic_fetch_add(cnt + (blockIdx.x & 7) * 32, 1,
                               __ATOMIC_RELAXED, __HIP_MEMORY_SCOPE_AGENT);
    if (threadIdx.x < 8) {
        const int target = gen * (NWG / 8);
        while (load_i32_sc(cnt + threadIdx.x * 32) < target)
            __builtin_amdgcn_s_sleep(2);
    }
    __syncthreads();
}

// ---------------------------------------------------------------------------
// Split-pack 4 fp32 into truncated-hi bf16 and residual-lo bf16 (packed).
// ---------------------------------------------------------------------------
__device__ inline void splitpack(float4 v, uint2& hi, uint2& lo) {
    unsigned u0 = __float_as_uint(v.x), u1 = __float_as_uint(v.y);
    unsigned u2 = __float_as_uint(v.z), u3 = __float_as_uint(v.w);
    hi.x = __builtin_amdgcn_perm(u1, u0, 0x07060302u);
    hi.y = __builtin_amdgcn_perm(u3, u2, 0x07060302u);
    float l0 = v.x - __uint_as_float(u0 & 0xFFFF0000u);
    float l1 = v.y - __uint_as_float(u1 & 0xFFFF0000u);
    float l2 = v.z - __uint_as_float(u2 & 0xFFFF0000u);
    float l3 = v.w - __uint_as_float(u3 & 0xFFFF0000u);
    lo.x = __builtin_amdgcn_perm(__float_as_uint(l1), __float_as_uint(l0), 0x07060302u);
    lo.y = __builtin_amdgcn_perm(__float_as_uint(l3), __float_as_uint(l2), 0x07060302u);
}

__device__ __forceinline__ bf16x8 ld8(const unsigned short* p) {
    return __builtin_bit_cast(bf16x8, *(const ushort8*)p);
}
__device__ __forceinline__ f32x4 mfma3(f32x4 acc, bf16x8 ah, bf16x8 al,
                                       bf16x8 bh, bf16x8 bl) {
    acc = __builtin_amdgcn_mfma_f32_16x16x32_bf16(ah, bh, acc, 0, 0, 0);
    acc = __builtin_amdgcn_mfma_f32_16x16x32_bf16(al, bh, acc, 0, 0, 0);
    acc = __builtin_amdgcn_mfma_f32_16x16x32_bf16(ah, bl, acc, 0, 0, 0);
    return acc;
}

// ---------------------------------------------------------------------------
// Split-bf16 MFMA GEMM with optional row gather + column offset (proven R2-R8).
// ---------------------------------------------------------------------------
__global__ __launch_bounds__(256) void gemm_mfma_split(
    const float* __restrict__ A, const float* __restrict__ W,
    const float* __restrict__ bias, float* __restrict__ C,
    const int* __restrict__ rowidx,
    int M, int N, int K, int lda, int ldbw, int ldc, int coff)
{
    __shared__ __align__(16) unsigned short Ah[128 * 40];
    __shared__ __align__(16) unsigned short Al[128 * 40];
    __shared__ __align__(16) unsigned short Bh[128 * 40];
    __shared__ __align__(16) unsigned short Bl[128 * 40];

    const int tid  = threadIdx.x;
    const int lane = tid & 63;
    const int wv   = tid >> 6;
    const int wm   = wv & 1, wn = wv >> 1;
    const int bn = blockIdx.x * 128;
    const int bm = blockIdx.y * 128;

    const float* apt[4];
    const float* bpt[4];
    bool bok[4];
    unsigned lofs[4];
    #pragma unroll
    for (int i = 0; i < 4; ++i) {
        int f4 = i * 256 + tid, r = f4 >> 3, kq = f4 & 7;
        int gm = bm + r;
        int ar = rowidx ? rowidx[gm] : gm;
        apt[i] = A + (size_t)ar * lda + kq * 4;
        int gn = bn + r;
        bok[i] = (gn < N);
        bpt[i] = W + (size_t)(bok[i] ? gn : 0) * ldbw + kq * 4;
        lofs[i] = r * 40 + kq * 4;
    }

    f32x4 acc[4][4];
    #pragma unroll
    for (int i = 0; i < 4; ++i)
        #pragma unroll
        for (int j = 0; j < 4; ++j) acc[i][j] = (f32x4){0.f, 0.f, 0.f, 0.f};

    const int la  = lane & 15;
    const int kg8 = (lane >> 4) * 8;

    for (int k0 = 0; k0 < K; k0 += 32) {
        __syncthreads();
        #pragma unroll
        for (int i = 0; i < 4; ++i) {
            float4 va = *(const float4*)(apt[i] + k0);
            uint2 h, l;
            splitpack(va, h, l);
            *(uint2*)&Ah[lofs[i]] = h;
            *(uint2*)&Al[lofs[i]] = l;
            float4 vb = {0.f, 0.f, 0.f, 0.f};
            if (bok[i]) vb = *(const float4*)(bpt[i] + k0);
            splitpack(vb, h, l);
            *(uint2*)&Bh[lofs[i]] = h;
            *(uint2*)&Bl[lofs[i]] = l;
        }
        __syncthreads();

        bf16x8 ah[4], al[4];
        #pragma unroll
        for (int mt = 0; mt < 4; ++mt) {
            int row = (wm * 64 + mt * 16 + la) * 40 + kg8;
            ah[mt] = ld8(&Ah[row]);
            al[mt] = ld8(&Al[row]);
        }
        #pragma unroll
        for (int nt = 0; nt < 4; ++nt) {
            int row = (wn * 64 + nt * 16 + la) * 40 + kg8;
            bf16x8 bh = ld8(&Bh[row]);
            bf16x8 bl = ld8(&Bl[row]);
            #pragma unroll
            for (int mt = 0; mt < 4; ++mt)
                acc[mt][nt] = mfma3(acc[mt][nt], ah[mt], al[mt], bh, bl);
        }
    }

    #pragma unroll
    for (int mt = 0; mt < 4; ++mt) {
        int mrow = bm + wm * 64 + mt * 16 + (lane >> 4) * 4;
        #pragma unroll
        for (int nt = 0; nt < 4; ++nt) {
            int n = bn + wn * 64 + nt * 16 + la;
            if (n < N) {
                float bi = bias ? bias[n] : 0.f;
                #pragma unroll
                for (int r = 0; r < 4; ++r)
                    C[(size_t)(mrow + r) * ldc + n + coff] = acc[mt][nt][r] + bi;
            }
        }
    }
}

// ---------------------------------------------------------------------------
// Prepass: split one fp32 matrix into bf16 hi/lo.
// ---------------------------------------------------------------------------
__global__ __launch_bounds__(256) void split_mat(
    const float* __restrict__ U, unsigned short* __restrict__ hi,
    unsigned short* __restrict__ lo, int nf4)
{
    int idx = blockIdx.x * 256 + threadIdx.x;
    if (idx >= nf4) return;
    float4 v = ((const float4*)U)[idx];
    uint2 h, l;
    splitpack(v, h, l);
    ((uint2*)hi)[idx] = h;
    ((uint2*)lo)[idx] = l;
}

// ---------------------------------------------------------------------------
// Persistent single-layer GRU, XCD-resident U (1.5 MB/XCD << 4 MiB L2).
// 256 blocks: xcd = bid&7; sub = bid>>3; m-tile = (sub&3)*16 rows;
// col-slice j0 = (xcd*8 + (sub>>2))*16. Waves = 4 k-quarters, LDS reduce.
// Per phase: stage full 16x1024 h-tile (split hi/lo) -> MFMA -> reduce ->
// epilogue on wave 0 (Wx/h scalars prefetched at phase top).
// Cross-block state via sc0sc1 stores + cached reads; 2 gridbars/step.
// ---------------------------------------------------------------------------
__global__ __launch_bounds__(256, 1) void gru_layer(
    const unsigned short* __restrict__ Uhi, const unsigned short* __restrict__ Ulo,
    const float* __restrict__ Wx, const float* __restrict__ hinit,
    float* __restrict__ hRM, float* __restrict__ rhRM,
    float* __restrict__ hfin, int* cnt)
{
    extern __shared__ char smem[];
    unsigned short* hs_hi = (unsigned short*)smem;       // 16*LDK
    unsigned short* hs_lo = hs_hi + 16 * LDK;
    f32x4* red = (f32x4*)(hs_lo + 16 * LDK);             // 6*64 f32x4

    const int tid  = threadIdx.x;
    const int lane = tid & 63;
    const int kh   = __builtin_amdgcn_readfirstlane(tid >> 6);  // k-quarter
    const int la   = lane & 15;
    const int kg8  = (lane >> 4) * 8;
    const int erow = (lane >> 4) * 4;
    const int trow = tid >> 4;      // staging row 0..15
    const int tq   = tid & 15;      // staging f4 col group

    const int bid = blockIdx.x;
    const int xcd = bid & 7;
    const int sub = bid >> 3;
    const int m0  = (sub & 3) * 16;
    const int j0  = (xcd * 8 + (sub >> 2)) * 16;

    const size_t HH = (size_t)H * H;
    const unsigned short* Ur_hi = Uhi;
    const unsigned short* Uz_hi = Uhi + HH;
    const unsigned short* Uh_hi = Uhi + 2 * HH;
    const unsigned short* Ur_lo = Ulo;
    const unsigned short* Uz_lo = Ulo + HH;
    const unsigned short* Uh_lo = Ulo + 2 * HH;

    int gen = 0;
    f32x4 zreg = (f32x4){0.f, 0.f, 0.f, 0.f};
    f32x4 wreg = (f32x4){0.f, 0.f, 0.f, 0.f};
    float hv[4] = {0.f, 0.f, 0.f, 0.f};

    for (int t = 0; t < T; ++t) {
        const float* hprev = (t == 0) ? hinit : (hRM + (size_t)(t - 1) * B * H);
        const int rbase = m0 + erow;

        // ================= phase A: r, z =================
        {
            float wr[4], wz[4];
            if (kh == 0) {
                #pragma unroll
                for (int qq = 0; qq < 4; ++qq) {
                    const size_t wb = ((size_t)t * B + rbase + qq) * (3 * H) + j0 + la;
                    wr[qq] = Wx[wb];
                    wz[qq] = Wx[wb + H];
                    wreg[qq] = Wx[wb + 2 * H];
                    hv[qq] = hprev[(size_t)(rbase + qq) * H + j0 + la];
                }
            }
            // stage h m-tile (16 rows x 1024) -> LDS split hi/lo
            {
                const float* hrp = hprev + (size_t)(m0 + trow) * H;
                #pragma unroll
                for (int i = 0; i < 16; ++i) {
                    const int c = (tq + i * 16) * 4;
                    float4 v = *(const float4*)(hrp + c);
                    uint2 h2, l2;
                    splitpack(v, h2, l2);
                    *(uint2*)&hs_hi[trow * LDK + c] = h2;
                    *(uint2*)&hs_lo[trow * LDK + c] = l2;
                }
            }
            __syncthreads();
            f32x4 a0 = (f32x4){0.f, 0.f, 0.f, 0.f}, a1 = a0;
            const int kb = kh * 256 + kg8;
            #pragma unroll
            for (int ks = 0; ks < 8; ++ks) {
                const int ko = kb + ks * 32;
                const int ar = la * LDK + ko;
                bf16x8 ah = ld8(&hs_hi[ar]);
                bf16x8 al = ld8(&hs_lo[ar]);
                const size_t ub = (size_t)(j0 + la) * H + ko;
                a0 = mfma3(a0, ah, al, ld8(Ur_hi + ub), ld8(Ur_lo + ub));
                a1 = mfma3(a1, ah, al, ld8(Uz_hi + ub), ld8(Uz_lo + ub));
            }
            if (kh) {
                red[((kh - 1) * 2 + 0) * 64 + lane] = a0;
                red[((kh - 1) * 2 + 1) * 64 + lane] = a1;
            }
            __syncthreads();
            if (kh == 0) {
                #pragma unroll
                for (int w = 0; w < 3; ++w) {
                    a0 += red[(w * 2 + 0) * 64 + lane];
                    a1 += red[(w * 2 + 1) * 64 + lane];
                }
                #pragma unroll
                for (int qq = 0; qq < 4; ++qq) {
                    float rg = 1.f / (1.f + __expf(-(a0[qq] + wr[qq])));
                    zreg[qq] = 1.f / (1.f + __expf(-(a1[qq] + wz[qq])));
                    store_f32_sc(rhRM + ((size_t)t * B + rbase + qq) * H + j0 + la,
                                 rg * hv[qq]);
                }
            }
        }
        gridbar(cnt, ++gen);

        // ================= phase B: h~ and update =================
        {
            // stage rh m-tile
            {
                const float* rrp = rhRM + (size_t)t * B * H + (size_t)(m0 + trow) * H;
                #pragma unroll
                for (int i = 0; i < 16; ++i) {
                    const int c = (tq + i * 16) * 4;
                    float4 v = *(const float4*)(rrp + c);
                    uint2 h2, l2;
                    splitpack(v, h2, l2);
                    *(uint2*)&hs_hi[trow * LDK + c] = h2;
                    *(uint2*)&hs_lo[trow * LDK + c] = l2;
                }
            }
            __syncthreads();
            f32x4 a = (f32x4){0.f, 0.f, 0.f, 0.f};
            const int kb = kh * 256 + kg8;
            #pragma unroll
            for (int ks = 0; ks < 8; ++ks) {
                const int ko = kb + ks * 32;
                const int ar = la * LDK + ko;
                const size_t ub = (size_t)(j0 + la) * H + ko;
                a = mfma3(a, ld8(&hs_hi[ar]), ld8(&hs_lo[ar]),
                          ld8(Uh_hi + ub), ld8(Uh_lo + ub));
            }
            if (kh) red[(kh - 1) * 64 + lane] = a;
            __syncthreads();
            if (kh == 0) {
                #pragma unroll
                for (int w = 0; w < 3; ++w) a += red[w * 64 + lane];
                #pragma unroll
                for (int qq = 0; qq < 4; ++qq) {
                    float ht = tanhf(a[qq] + wreg[qq]);
                    float hn = (1.f - zreg[qq]) * hv[qq] + zreg[qq] * ht;
                    store_f32_sc(hRM + ((size_t)t * B + rbase + qq) * H + j0 + la, hn);
                    if (t == T - 1)
                        store_f32_sc(hfin + (size_t)(rbase + qq) * H + j0 + la, hn);
                }
            }
        }
        gridbar(cnt, ++gen);
    }
}

// ---------------------------------------------------------------------------
extern "C" void kernel_launch(void* const* d_in, const int* in_sizes, int n_in,
                              void* d_out, int out_size, void* d_ws, size_t ws_size,
                              hipStream_t stream)
{
    const int*   tok    = (const int*)d_in[0];
    const float* hidden = (const float*)d_in[1];
    const float* emb    = (const float*)d_in[2];
    const float* Wr0 = (const float*)d_in[3],  *br0 = (const float*)d_in[4];
    const float* Wz0 = (const float*)d_in[5],  *bz0 = (const float*)d_in[6];
    const float* Wh0 = (const float*)d_in[7],  *bh0 = (const float*)d_in[8];
    const float* Ur0 = (const float*)d_in[9],  *Uz0 = (const float*)d_in[10], *Uh0 = (const float*)d_in[11];
    const float* Wr1 = (const float*)d_in[12], *br1 = (const float*)d_in[13];
    const float* Wz1 = (const float*)d_in[14], *bz1 = (const float*)d_in[15];
    const float* Wh1 = (const float*)d_in[16], *bh1 = (const float*)d_in[17];
    const float* Ur1 = (const float*)d_in[18], *Uz1 = (const float*)d_in[19], *Uh1 = (const float*)d_in[20];
    const float* Wout = (const float*)d_in[21], *bout = (const float*)d_in[22];
    float* out = (float*)d_out;

    const size_t HH = (size_t)H * H;

    float* ws    = (float*)d_ws;
    float* Wx    = ws;                                   // T*B*3H (shared L0/L1)
    float* h0RM  = Wx    + (size_t)T * B * 3 * H;        // T*B*H
    float* rh0RM = h0RM  + (size_t)T * B * H;
    float* h1RM  = rh0RM + (size_t)T * B * H;
    float* rh1RM = h1RM  + (size_t)T * B * H;
    unsigned short* U0hi = (unsigned short*)(rh1RM + (size_t)T * B * H);
    unsigned short* U0lo = U0hi + 3 * HH;
    unsigned short* U1hi = U0lo + 3 * HH;
    unsigned short* U1lo = U1hi + 3 * HH;
    int* cnt0 = (int*)(U1lo + 3 * HH);                   // 256 ints
    int* cnt1 = cnt0 + 256;

    static bool attr_set = false;
    if (!attr_set) {
        (void)hipFuncSetAttribute((const void*)gru_layer,
                                  hipFuncAttributeMaxDynamicSharedMemorySize, 138240);
        attr_set = true;
    }

    (void)hipMemsetAsync(cnt0, 0, 512 * sizeof(int), stream);

    const int nHH = (int)(HH / 4);
    split_mat<<<nHH / 256, 256, 0, stream>>>(Ur0, U0hi + 0 * HH, U0lo + 0 * HH, nHH);
    split_mat<<<nHH / 256, 256, 0, stream>>>(Uz0, U0hi + 1 * HH, U0lo + 1 * HH, nHH);
    split_mat<<<nHH / 256, 256, 0, stream>>>(Uh0, U0hi + 2 * HH, U0lo + 2 * HH, nHH);
    split_mat<<<nHH / 256, 256, 0, stream>>>(Ur1, U1hi + 0 * HH, U1lo + 0 * HH, nHH);
    split_mat<<<nHH / 256, 256, 0, stream>>>(Uz1, U1hi + 1 * HH, U1lo + 1 * HH, nHH);
    split_mat<<<nHH / 256, 256, 0, stream>>>(Uh1, U1hi + 2 * HH, U1lo + 2 * HH, nHH);

    // ---- Wx(L0) = emb[tok] @ [Wr0;Wz0;Wh0]^T + b (gather fused, bias folded)
    gemm_mfma_split<<<dim3(H / 128, T * B / 128), 256, 0, stream>>>(emb, Wr0, br0, Wx, tok, T * B, H, E, E, E, 3 * H, 0);
    gemm_mfma_split<<<dim3(H / 128, T * B / 128), 256, 0, stream>>>(emb, Wz0, bz0, Wx, tok, T * B, H, E, E, E, 3 * H, H);
    gemm_mfma_split<<<dim3(H / 128, T * B / 128), 256, 0, stream>>>(emb, Wh0, bh0, Wx, tok, T * B, H, E, E, E, 3 * H, 2 * H);

    gru_layer<<<NWG, 256, 138240, stream>>>(U0hi, U0lo, Wx, hidden,
                                            h0RM, rh0RM, out + (size_t)T * B * V, cnt0);

    // ---- Wx(L1) = h0_seq @ [Wr1;Wz1;Wh1]^T + b
    gemm_mfma_split<<<dim3(H / 128, T * B / 128), 256, 0, stream>>>(h0RM, Wr1, br1, Wx, nullptr, T * B, H, H, H, H, 3 * H, 0);
    gemm_mfma_split<<<dim3(H / 128, T * B / 128), 256, 0, stream>>>(h0RM, Wz1, bz1, Wx, nullptr, T * B, H, H, H, H, 3 * H, H);
    gemm_mfma_split<<<dim3(H / 128, T * B / 128), 256, 0, stream>>>(h0RM, Wh1, bh1, Wx, nullptr, T * B, H, H, H, H, 3 * H, 2 * H);

    gru_layer<<<NWG, 256, 138240, stream>>>(U1hi, U1lo, Wx, hidden + (size_t)B * H,
                                            h1RM, rh1RM,
                                            out + (size_t)T * B * V + (size_t)B * H, cnt1);

    // ---- logits = h1_seq @ Wout^T + bout
    gemm_mfma_split<<<dim3((V + 127) / 128, T * B / 128), 256, 0, stream>>>(
        h1RM, Wout, bout, out, nullptr, T * B, V, H, H, H, V, 0);
}

// Round 11
// 4469.912 us; speedup vs baseline: 2.0960x; 1.2411x over previous
//
#include <hip/hip_runtime.h>
#include <hip/hip_bf16.h>
#include <math.h>

#define V 10000
#define E 512
#define H 1024
#define T 128
#define B 64
#define NWG 256
#define LDK 1032   // LDS row stride in ushorts (2064 B -> benign 2-lane/bank aliasing)

typedef __bf16 bf16x8 __attribute__((ext_vector_type(8)));
typedef float f32x4 __attribute__((ext_vector_type(4)));
typedef unsigned short ushort8 __attribute__((ext_vector_type(8)));

// ---------------------------------------------------------------------------
// Cache-bypassing (coherent-at-MALL) access helpers (validated R4-R10).
// ---------------------------------------------------------------------------
__device__ __forceinline__ void store_f32_sc(float* p, float v) {
    asm volatile("global_store_dword %0, %1, off sc0 sc1" :: "v"(p), "v"(v) : "memory");
}
__device__ __forceinline__ int load_i32_sc(const int* p) {
    int r;
    asm volatile("global_load_dword %0, %1, off sc0 sc1\n\ts_waitcnt vmcnt(0)"
                 : "=v"(r) : "v"(p) : "memory");
    return r;
}

// ---------------------------------------------------------------------------
// Fence-free grid barrier: 8 striped counters (validated R4-R10).
// ---------------------------------------------------------------------------
__device__ __forceinline__ void gridbar(int* cnt, int gen) {
    asm volatile("s_waitcnt vmcnt(0)" ::: "memory");
    __syncthreads();
    if (threadIdx.x == 0)
        __hip_atomic_fetch_add(cnt + (blockIdx.x & 7) * 32, 1,
                               __ATOMIC_RELAXED, __HIP_MEMORY_SCOPE_AGENT);
    if (threadIdx.x < 8) {
        const int target = gen * (NWG / 8);
        while (load_i32_sc(cnt + threadIdx.x * 32) < target)
            __builtin_amdgcn_s_sleep(2);
    }
    __syncthreads();
}

// ---------------------------------------------------------------------------
// Split-pack 4 fp32 into truncated-hi bf16 and residual-lo bf16 (packed).
// ---------------------------------------------------------------------------
__device__ inline void splitpack(float4 v, uint2& hi, uint2& lo) {
    unsigned u0 = __float_as_uint(v.x), u1 = __float_as_uint(v.y);
    unsigned u2 = __float_as_uint(v.z), u3 = __float_as_uint(v.w);
    hi.x = __builtin_amdgcn_perm(u1, u0, 0x07060302u);
    hi.y = __builtin_amdgcn_perm(u3, u2, 0x07060302u);
    float l0 = v.x - __uint_as_float(u0 & 0xFFFF0000u);
    float l1 = v.y - __uint_as_float(u1 & 0xFFFF0000u);
    float l2 = v.z - __uint_as_float(u2 & 0xFFFF0000u);
    float l3 = v.w - __uint_as_float(u3 & 0xFFFF0000u);
    lo.x = __builtin_amdgcn_perm(__float_as_uint(l1), __float_as_uint(l0), 0x07060302u);
    lo.y = __builtin_amdgcn_perm(__float_as_uint(l3), __float_as_uint(l2), 0x07060302u);
}

__device__ __forceinline__ bf16x8 ld8(const unsigned short* p) {
    return __builtin_bit_cast(bf16x8, *(const ushort8*)p);
}
__device__ __forceinline__ f32x4 mfma3(f32x4 acc, bf16x8 ah, bf16x8 al,
                                       bf16x8 bh, bf16x8 bl) {
    acc = __builtin_amdgcn_mfma_f32_16x16x32_bf16(ah, bh, acc, 0, 0, 0);
    acc = __builtin_amdgcn_mfma_f32_16x16x32_bf16(al, bh, acc, 0, 0, 0);
    acc = __builtin_amdgcn_mfma_f32_16x16x32_bf16(ah, bl, acc, 0, 0, 0);
    return acc;
}

// ---------------------------------------------------------------------------
// Split-bf16 MFMA GEMM with optional row gather + column offset (proven R2-R10).
// ---------------------------------------------------------------------------
__global__ __launch_bounds__(256) void gemm_mfma_split(
    const float* __restrict__ A, const float* __restrict__ W,
    const float* __restrict__ bias, float* __restrict__ C,
    const int* __restrict__ rowidx,
    int M, int N, int K, int lda, int ldbw, int ldc, int coff)
{
    __shared__ __align__(16) unsigned short Ah[128 * 40];
    __shared__ __align__(16) unsigned short Al[128 * 40];
    __shared__ __align__(16) unsigned short Bh[128 * 40];
    __shared__ __align__(16) unsigned short Bl[128 * 40];

    const int tid  = threadIdx.x;
    const int lane = tid & 63;
    const int wv   = tid >> 6;
    const int wm   = wv & 1, wn = wv >> 1;
    const int bn = blockIdx.x * 128;
    const int bm = blockIdx.y * 128;

    const float* apt[4];
    const float* bpt[4];
    bool bok[4];
    unsigned lofs[4];
    #pragma unroll
    for (int i = 0; i < 4; ++i) {
        int f4 = i * 256 + tid, r = f4 >> 3, kq = f4 & 7;
        int gm = bm + r;
        int ar = rowidx ? rowidx[gm] : gm;
        apt[i] = A + (size_t)ar * lda + kq * 4;
        int gn = bn + r;
        bok[i] = (gn < N);
        bpt[i] = W + (size_t)(bok[i] ? gn : 0) * ldbw + kq * 4;
        lofs[i] = r * 40 + kq * 4;
    }

    f32x4 acc[4][4];
    #pragma unroll
    for (int i = 0; i < 4; ++i)
        #pragma unroll
        for (int j = 0; j < 4; ++j) acc[i][j] = (f32x4){0.f, 0.f, 0.f, 0.f};

    const int la  = lane & 15;
    const int kg8 = (lane >> 4) * 8;

    for (int k0 = 0; k0 < K; k0 += 32) {
        __syncthreads();
        #pragma unroll
        for (int i = 0; i < 4; ++i) {
            float4 va = *(const float4*)(apt[i] + k0);
            uint2 h, l;
            splitpack(va, h, l);
            *(uint2*)&Ah[lofs[i]] = h;
            *(uint2*)&Al[lofs[i]] = l;
            float4 vb = {0.f, 0.f, 0.f, 0.f};
            if (bok[i]) vb = *(const float4*)(bpt[i] + k0);
            splitpack(vb, h, l);
            *(uint2*)&Bh[lofs[i]] = h;
            *(uint2*)&Bl[lofs[i]] = l;
        }
        __syncthreads();

        bf16x8 ah[4], al[4];
        #pragma unroll
        for (int mt = 0; mt < 4; ++mt) {
            int row = (wm * 64 + mt * 16 + la) * 40 + kg8;
            ah[mt] = ld8(&Ah[row]);
            al[mt] = ld8(&Al[row]);
        }
        #pragma unroll
        for (int nt = 0; nt < 4; ++nt) {
            int row = (wn * 64 + nt * 16 + la) * 40 + kg8;
            bf16x8 bh = ld8(&Bh[row]);
            bf16x8 bl = ld8(&Bl[row]);
            #pragma unroll
            for (int mt = 0; mt < 4; ++mt)
                acc[mt][nt] = mfma3(acc[mt][nt], ah[mt], al[mt], bh, bl);
        }
    }

    #pragma unroll
    for (int mt = 0; mt < 4; ++mt) {
        int mrow = bm + wm * 64 + mt * 16 + (lane >> 4) * 4;
        #pragma unroll
        for (int nt = 0; nt < 4; ++nt) {
            int n = bn + wn * 64 + nt * 16 + la;
            if (n < N) {
                float bi = bias ? bias[n] : 0.f;
                #pragma unroll
                for (int r = 0; r < 4; ++r)
                    C[(size_t)(mrow + r) * ldc + n + coff] = acc[mt][nt][r] + bi;
            }
        }
    }
}

// ---------------------------------------------------------------------------
// Prepass: split one fp32 matrix into bf16 hi/lo.
// ---------------------------------------------------------------------------
__global__ __launch_bounds__(256) void split_mat(
    const float* __restrict__ U, unsigned short* __restrict__ hi,
    unsigned short* __restrict__ lo, int nf4)
{
    int idx = blockIdx.x * 256 + threadIdx.x;
    if (idx >= nf4) return;
    float4 v = ((const float4*)U)[idx];
    uint2 h, l;
    splitpack(v, h, l);
    ((uint2*)hi)[idx] = h;
    ((uint2*)lo)[idx] = l;
}

// ---------------------------------------------------------------------------
// Persistent single-layer GRU, XCD-resident U (1.5 MB/XCD << 4 MiB L2).
// 256 blocks x 512 threads (8 waves = 2/SIMD for latency hiding).
// xcd = bid&7; sub = bid>>3; m-tile = (sub&3)*16 rows; j0 = (xcd*8+(sub>>2))*16.
// Waves = 8 k-eighths (128-wide each), 7-deep LDS reduce, wave-0 epilogue.
// Cross-block state via sc0sc1 stores + fresh-address cached reads.
// ---------------------------------------------------------------------------
__global__ __launch_bounds__(512, 1) void gru_layer(
    const unsigned short* __restrict__ Uhi, const unsigned short* __restrict__ Ulo,
    const float* __restrict__ Wx, const float* __restrict__ hinit,
    float* __restrict__ hRM, float* __restrict__ rhRM,
    float* __restrict__ hfin, int* cnt)
{
    extern __shared__ char smem[];
    unsigned short* hs_hi = (unsigned short*)smem;       // 16*LDK
    unsigned short* hs_lo = hs_hi + 16 * LDK;
    f32x4* red = (f32x4*)(hs_lo + 16 * LDK);             // 14*64 f32x4

    const int tid  = threadIdx.x;
    const int lane = tid & 63;
    const int kh   = __builtin_amdgcn_readfirstlane(tid >> 6);  // k-eighth 0..7
    const int la   = lane & 15;
    const int kg8  = (lane >> 4) * 8;
    const int erow = (lane >> 4) * 4;
    const int trow = tid >> 5;      // staging row 0..15
    const int tq   = tid & 31;      // staging f4 col group

    const int bid = blockIdx.x;
    const int xcd = bid & 7;
    const int sub = bid >> 3;
    const int m0  = (sub & 3) * 16;
    const int j0  = (xcd * 8 + (sub >> 2)) * 16;

    const size_t HH = (size_t)H * H;
    const unsigned short* Ur_hi = Uhi;
    const unsigned short* Uz_hi = Uhi + HH;
    const unsigned short* Uh_hi = Uhi + 2 * HH;
    const unsigned short* Ur_lo = Ulo;
    const unsigned short* Uz_lo = Ulo + HH;
    const unsigned short* Uh_lo = Ulo + 2 * HH;

    int gen = 0;
    f32x4 zreg = (f32x4){0.f, 0.f, 0.f, 0.f};
    f32x4 wreg = (f32x4){0.f, 0.f, 0.f, 0.f};
    float hv[4] = {0.f, 0.f, 0.f, 0.f};

    for (int t = 0; t < T; ++t) {
        const float* hprev = (t == 0) ? hinit : (hRM + (size_t)(t - 1) * B * H);
        const int rbase = m0 + erow;

        // ================= phase A: r, z =================
        {
            float wr[4], wz[4];
            if (kh == 0) {
                #pragma unroll
                for (int qq = 0; qq < 4; ++qq) {
                    const size_t wb = ((size_t)t * B + rbase + qq) * (3 * H) + j0 + la;
                    wr[qq] = Wx[wb];
                    wz[qq] = Wx[wb + H];
                    wreg[qq] = Wx[wb + 2 * H];
                    hv[qq] = hprev[(size_t)(rbase + qq) * H + j0 + la];
                }
            }
            // stage h m-tile (16 rows x 1024 fp32) -> LDS split hi/lo
            {
                const float* hrp = hprev + (size_t)(m0 + trow) * H;
                #pragma unroll
                for (int i = 0; i < 8; ++i) {
                    const int c = (tq + i * 32) * 4;
                    float4 v = *(const float4*)(hrp + c);
                    uint2 h2, l2;
                    splitpack(v, h2, l2);
                    *(uint2*)&hs_hi[trow * LDK + c] = h2;
                    *(uint2*)&hs_lo[trow * LDK + c] = l2;
                }
            }
            __syncthreads();
            f32x4 a0 = (f32x4){0.f, 0.f, 0.f, 0.f}, a1 = a0;
            const int kb = kh * 128 + kg8;
            #pragma unroll
            for (int ks = 0; ks < 4; ++ks) {
                const int ko = kb + ks * 32;
                const int ar = la * LDK + ko;
                bf16x8 ah = ld8(&hs_hi[ar]);
                bf16x8 al = ld8(&hs_lo[ar]);
                const size_t ub = (size_t)(j0 + la) * H + ko;
                a0 = mfma3(a0, ah, al, ld8(Ur_hi + ub), ld8(Ur_lo + ub));
                a1 = mfma3(a1, ah, al, ld8(Uz_hi + ub), ld8(Uz_lo + ub));
            }
            if (kh) {
                red[((kh - 1) * 2 + 0) * 64 + lane] = a0;
                red[((kh - 1) * 2 + 1) * 64 + lane] = a1;
            }
            __syncthreads();
            if (kh == 0) {
                #pragma unroll
                for (int w = 0; w < 7; ++w) {
                    a0 += red[(w * 2 + 0) * 64 + lane];
                    a1 += red[(w * 2 + 1) * 64 + lane];
                }
                #pragma unroll
                for (int qq = 0; qq < 4; ++qq) {
                    float rg = 1.f / (1.f + __expf(-(a0[qq] + wr[qq])));
                    zreg[qq] = 1.f / (1.f + __expf(-(a1[qq] + wz[qq])));
                    store_f32_sc(rhRM + ((size_t)t * B + rbase + qq) * H + j0 + la,
                                 rg * hv[qq]);
                }
            }
        }
        gridbar(cnt, ++gen);

        // ================= phase B: h~ and update =================
        {
            // stage rh m-tile
            {
                const float* rrp = rhRM + (size_t)t * B * H + (size_t)(m0 + trow) * H;
                #pragma unroll
                for (int i = 0; i < 8; ++i) {
                    const int c = (tq + i * 32) * 4;
                    float4 v = *(const float4*)(rrp + c);
                    uint2 h2, l2;
                    splitpack(v, h2, l2);
                    *(uint2*)&hs_hi[trow * LDK + c] = h2;
                    *(uint2*)&hs_lo[trow * LDK + c] = l2;
                }
            }
            __syncthreads();
            f32x4 a = (f32x4){0.f, 0.f, 0.f, 0.f};
            const int kb = kh * 128 + kg8;
            #pragma unroll
            for (int ks = 0; ks < 4; ++ks) {
                const int ko = kb + ks * 32;
                const int ar = la * LDK + ko;
                const size_t ub = (size_t)(j0 + la) * H + ko;
                a = mfma3(a, ld8(&hs_hi[ar]), ld8(&hs_lo[ar]),
                          ld8(Uh_hi + ub), ld8(Uh_lo + ub));
            }
            if (kh) red[(kh - 1) * 64 + lane] = a;
            __syncthreads();
            if (kh == 0) {
                #pragma unroll
                for (int w = 0; w < 7; ++w) a += red[w * 64 + lane];
                #pragma unroll
                for (int qq = 0; qq < 4; ++qq) {
                    float ht = tanhf(a[qq] + wreg[qq]);
                    float hn = (1.f - zreg[qq]) * hv[qq] + zreg[qq] * ht;
                    store_f32_sc(hRM + ((size_t)t * B + rbase + qq) * H + j0 + la, hn);
                    if (t == T - 1)
                        store_f32_sc(hfin + (size_t)(rbase + qq) * H + j0 + la, hn);
                }
            }
        }
        gridbar(cnt, ++gen);
    }
}

// ---------------------------------------------------------------------------
extern "C" void kernel_launch(void* const* d_in, const int* in_sizes, int n_in,
                              void* d_out, int out_size, void* d_ws, size_t ws_size,
                              hipStream_t stream)
{
    const int*   tok    = (const int*)d_in[0];
    const float* hidden = (const float*)d_in[1];
    const float* emb    = (const float*)d_in[2];
    const float* Wr0 = (const float*)d_in[3],  *br0 = (const float*)d_in[4];
    const float* Wz0 = (const float*)d_in[5],  *bz0 = (const float*)d_in[6];
    const float* Wh0 = (const float*)d_in[7],  *bh0 = (const float*)d_in[8];
    const float* Ur0 = (const float*)d_in[9],  *Uz0 = (const float*)d_in[10], *Uh0 = (const float*)d_in[11];
    const float* Wr1 = (const float*)d_in[12], *br1 = (const float*)d_in[13];
    const float* Wz1 = (const float*)d_in[14], *bz1 = (const float*)d_in[15];
    const float* Wh1 = (const float*)d_in[16], *bh1 = (const float*)d_in[17];
    const float* Ur1 = (const float*)d_in[18], *Uz1 = (const float*)d_in[19], *Uh1 = (const float*)d_in[20];
    const float* Wout = (const float*)d_in[21], *bout = (const float*)d_in[22];
    float* out = (float*)d_out;

    const size_t HH = (size_t)H * H;

    float* ws    = (float*)d_ws;
    float* Wx    = ws;                                   // T*B*3H (shared L0/L1)
    float* h0RM  = Wx    + (size_t)T * B * 3 * H;        // T*B*H
    float* rh0RM = h0RM  + (size_t)T * B * H;
    float* h1RM  = rh0RM + (size_t)T * B * H;
    float* rh1RM = h1RM  + (size_t)T * B * H;
    unsigned short* U0hi = (unsigned short*)(rh1RM + (size_t)T * B * H);
    unsigned short* U0lo = U0hi + 3 * HH;
    unsigned short* U1hi = U0lo + 3 * HH;
    unsigned short* U1lo = U1hi + 3 * HH;
    int* cnt0 = (int*)(U1lo + 3 * HH);                   // 256 ints
    int* cnt1 = cnt0 + 256;

    static bool attr_set = false;
    if (!attr_set) {
        (void)hipFuncSetAttribute((const void*)gru_layer,
                                  hipFuncAttributeMaxDynamicSharedMemorySize, 80384);
        attr_set = true;
    }

    (void)hipMemsetAsync(cnt0, 0, 512 * sizeof(int), stream);

    const int nHH = (int)(HH / 4);
    split_mat<<<nHH / 256, 256, 0, stream>>>(Ur0, U0hi + 0 * HH, U0lo + 0 * HH, nHH);
    split_mat<<<nHH / 256, 256, 0, stream>>>(Uz0, U0hi + 1 * HH, U0lo + 1 * HH, nHH);
    split_mat<<<nHH / 256, 256, 0, stream>>>(Uh0, U0hi + 2 * HH, U0lo + 2 * HH, nHH);
    split_mat<<<nHH / 256, 256, 0, stream>>>(Ur1, U1hi + 0 * HH, U1lo + 0 * HH, nHH);
    split_mat<<<nHH / 256, 256, 0, stream>>>(Uz1, U1hi + 1 * HH, U1lo + 1 * HH, nHH);
    split_mat<<<nHH / 256, 256, 0, stream>>>(Uh1, U1hi + 2 * HH, U1lo + 2 * HH, nHH);

    // ---- Wx(L0) = emb[tok] @ [Wr0;Wz0;Wh0]^T + b (gather fused, bias folded)
    gemm_mfma_split<<<dim3(H / 128, T * B / 128), 256, 0, stream>>>(emb, Wr0, br0, Wx, tok, T * B, H, E, E, E, 3 * H, 0);
    gemm_mfma_split<<<dim3(H / 128, T * B / 128), 256, 0, stream>>>(emb, Wz0, bz0, Wx, tok, T * B, H, E, E, E, 3 * H, H);
    gemm_mfma_split<<<dim3(H / 128, T * B / 128), 256, 0, stream>>>(emb, Wh0, bh0, Wx, tok, T * B, H, E, E, E, 3 * H, 2 * H);

    gru_layer<<<NWG, 512, 80384, stream>>>(U0hi, U0lo, Wx, hidden,
                                           h0RM, rh0RM, out + (size_t)T * B * V, cnt0);

    // ---- Wx(L1) = h0_seq @ [Wr1;Wz1;Wh1]^T + b
    gemm_mfma_split<<<dim3(H / 128, T * B / 128), 256, 0, stream>>>(h0RM, Wr1, br1, Wx, nullptr, T * B, H, H, H, H, 3 * H, 0);
    gemm_mfma_split<<<dim3(H / 128, T * B / 128), 256, 0, stream>>>(h0RM, Wz1, bz1, Wx, nullptr, T * B, H, H, H, H, 3 * H, H);
    gemm_mfma_split<<<dim3(H / 128, T * B / 128), 256, 0, stream>>>(h0RM, Wh1, bh1, Wx, nullptr, T * B, H, H, H, H, 3 * H, 2 * H);

    gru_layer<<<NWG, 512, 80384, stream>>>(U1hi, U1lo, Wx, hidden + (size_t)B * H,
                                           h1RM, rh1RM,
                                           out + (size_t)T * B * V + (size_t)B * H, cnt1);

    // ---- logits = h1_seq @ Wout^T + bout
    gemm_mfma_split<<<dim3((V + 127) / 128, T * B / 128), 256, 0, stream>>>(
        h1RM, Wout, bout, out, nullptr, T * B, V, H, H, H, V, 0);
}

// Round 12
// 4217.791 us; speedup vs baseline: 2.2213x; 1.0598x over previous
//
#include <hip/hip_runtime.h>
#include <hip/hip_bf16.h>
#include <math.h>

#define V 10000
#define E 512
#define H 1024
#define T 128
#define B 64
#define NWG 256
#define LDK 1032   // LDS row stride in ushorts (2064 B -> benign 2-lane/bank aliasing)

typedef __bf16 bf16x8 __attribute__((ext_vector_type(8)));
typedef float f32x4 __attribute__((ext_vector_type(4)));
typedef unsigned short ushort8 __attribute__((ext_vector_type(8)));

// ---------------------------------------------------------------------------
// Cache-bypassing (coherent-at-MALL) access helpers (validated R4-R11).
// ---------------------------------------------------------------------------
__device__ __forceinline__ void store_f32_sc(float* p, float v) {
    asm volatile("global_store_dword %0, %1, off sc0 sc1" :: "v"(p), "v"(v) : "memory");
}
__device__ __forceinline__ int load_i32_sc(const int* p) {
    int r;
    asm volatile("global_load_dword %0, %1, off sc0 sc1\n\ts_waitcnt vmcnt(0)"
                 : "=v"(r) : "v"(p) : "memory");
    return r;
}

// ---------------------------------------------------------------------------
// Per-m-tile-group grid barrier: 64 blocks/group (closed dependency set —
// GRU never mixes batch rows). 8 stripes (one per XCD), 8 arrivals each.
// ---------------------------------------------------------------------------
__device__ __forceinline__ void gridbar_grp(int* gcnt, int gen) {
    asm volatile("s_waitcnt vmcnt(0)" ::: "memory");
    __syncthreads();
    if (threadIdx.x == 0)
        __hip_atomic_fetch_add(gcnt + (blockIdx.x & 7) * 32, 1,
                               __ATOMIC_RELAXED, __HIP_MEMORY_SCOPE_AGENT);
    if (threadIdx.x < 8) {
        const int target = gen * 8;
        while (load_i32_sc(gcnt + threadIdx.x * 32) < target)
            __builtin_amdgcn_s_sleep(2);
    }
    __syncthreads();
}

// ---------------------------------------------------------------------------
// Split-pack 4 fp32 into truncated-hi bf16 and residual-lo bf16 (packed).
// ---------------------------------------------------------------------------
__device__ inline void splitpack(float4 v, uint2& hi, uint2& lo) {
    unsigned u0 = __float_as_uint(v.x), u1 = __float_as_uint(v.y);
    unsigned u2 = __float_as_uint(v.z), u3 = __float_as_uint(v.w);
    hi.x = __builtin_amdgcn_perm(u1, u0, 0x07060302u);
    hi.y = __builtin_amdgcn_perm(u3, u2, 0x07060302u);
    float l0 = v.x - __uint_as_float(u0 & 0xFFFF0000u);
    float l1 = v.y - __uint_as_float(u1 & 0xFFFF0000u);
    float l2 = v.z - __uint_as_float(u2 & 0xFFFF0000u);
    float l3 = v.w - __uint_as_float(u3 & 0xFFFF0000u);
    lo.x = __builtin_amdgcn_perm(__float_as_uint(l1), __float_as_uint(l0), 0x07060302u);
    lo.y = __builtin_amdgcn_perm(__float_as_uint(l3), __float_as_uint(l2), 0x07060302u);
}

__device__ __forceinline__ bf16x8 ld8(const unsigned short* p) {
    return __builtin_bit_cast(bf16x8, *(const ushort8*)p);
}
__device__ __forceinline__ f32x4 mfma3(f32x4 acc, bf16x8 ah, bf16x8 al,
                                       bf16x8 bh, bf16x8 bl) {
    acc = __builtin_amdgcn_mfma_f32_16x16x32_bf16(ah, bh, acc, 0, 0, 0);
    acc = __builtin_amdgcn_mfma_f32_16x16x32_bf16(al, bh, acc, 0, 0, 0);
    acc = __builtin_amdgcn_mfma_f32_16x16x32_bf16(ah, bl, acc, 0, 0, 0);
    return acc;
}

// ---------------------------------------------------------------------------
// Split-bf16 MFMA GEMM with optional row gather + column offset (proven R2-R11).
// ---------------------------------------------------------------------------
__global__ __launch_bounds__(256) void gemm_mfma_split(
    const float* __restrict__ A, const float* __restrict__ W,
    const float* __restrict__ bias, float* __restrict__ C,
    const int* __restrict__ rowidx,
    int M, int N, int K, int lda, int ldbw, int ldc, int coff)
{
    __shared__ __align__(16) unsigned short Ah[128 * 40];
    __shared__ __align__(16) unsigned short Al[128 * 40];
    __shared__ __align__(16) unsigned short Bh[128 * 40];
    __shared__ __align__(16) unsigned short Bl[128 * 40];

    const int tid  = threadIdx.x;
    const int lane = tid & 63;
    const int wv   = tid >> 6;
    const int wm   = wv & 1, wn = wv >> 1;
    const int bn = blockIdx.x * 128;
    const int bm = blockIdx.y * 128;

    const float* apt[4];
    const float* bpt[4];
    bool bok[4];
    unsigned lofs[4];
    #pragma unroll
    for (int i = 0; i < 4; ++i) {
        int f4 = i * 256 + tid, r = f4 >> 3, kq = f4 & 7;
        int gm = bm + r;
        int ar = rowidx ? rowidx[gm] : gm;
        apt[i] = A + (size_t)ar * lda + kq * 4;
        int gn = bn + r;
        bok[i] = (gn < N);
        bpt[i] = W + (size_t)(bok[i] ? gn : 0) * ldbw + kq * 4;
        lofs[i] = r * 40 + kq * 4;
    }

    f32x4 acc[4][4];
    #pragma unroll
    for (int i = 0; i < 4; ++i)
        #pragma unroll
        for (int j = 0; j < 4; ++j) acc[i][j] = (f32x4){0.f, 0.f, 0.f, 0.f};

    const int la  = lane & 15;
    const int kg8 = (lane >> 4) * 8;

    for (int k0 = 0; k0 < K; k0 += 32) {
        __syncthreads();
        #pragma unroll
        for (int i = 0; i < 4; ++i) {
            float4 va = *(const float4*)(apt[i] + k0);
            uint2 h, l;
            splitpack(va, h, l);
            *(uint2*)&Ah[lofs[i]] = h;
            *(uint2*)&Al[lofs[i]] = l;
            float4 vb = {0.f, 0.f, 0.f, 0.f};
            if (bok[i]) vb = *(const float4*)(bpt[i] + k0);
            splitpack(vb, h, l);
            *(uint2*)&Bh[lofs[i]] = h;
            *(uint2*)&Bl[lofs[i]] = l;
        }
        __syncthreads();

        bf16x8 ah[4], al[4];
        #pragma unroll
        for (int mt = 0; mt < 4; ++mt) {
            int row = (wm * 64 + mt * 16 + la) * 40 + kg8;
            ah[mt] = ld8(&Ah[row]);
            al[mt] = ld8(&Al[row]);
        }
        #pragma unroll
        for (int nt = 0; nt < 4; ++nt) {
            int row = (wn * 64 + nt * 16 + la) * 40 + kg8;
            bf16x8 bh = ld8(&Bh[row]);
            bf16x8 bl = ld8(&Bl[row]);
            #pragma unroll
            for (int mt = 0; mt < 4; ++mt)
                acc[mt][nt] = mfma3(acc[mt][nt], ah[mt], al[mt], bh, bl);
        }
    }

    #pragma unroll
    for (int mt = 0; mt < 4; ++mt) {
        int mrow = bm + wm * 64 + mt * 16 + (lane >> 4) * 4;
        #pragma unroll
        for (int nt = 0; nt < 4; ++nt) {
            int n = bn + wn * 64 + nt * 16 + la;
            if (n < N) {
                float bi = bias ? bias[n] : 0.f;
                #pragma unroll
                for (int r = 0; r < 4; ++r)
                    C[(size_t)(mrow + r) * ldc + n + coff] = acc[mt][nt][r] + bi;
            }
        }
    }
}

// ---------------------------------------------------------------------------
// Prepass: split one fp32 matrix into bf16 hi/lo.
// ---------------------------------------------------------------------------
__global__ __launch_bounds__(256) void split_mat(
    const float* __restrict__ U, unsigned short* __restrict__ hi,
    unsigned short* __restrict__ lo, int nf4)
{
    int idx = blockIdx.x * 256 + threadIdx.x;
    if (idx >= nf4) return;
    float4 v = ((const float4*)U)[idx];
    uint2 h, l;
    splitpack(v, h, l);
    ((uint2*)hi)[idx] = h;
    ((uint2*)lo)[idx] = l;
}

// ---------------------------------------------------------------------------
// Persistent single-layer GRU. XCD-resident U; 4 independent m-tile groups
// with 64-block group barriers. 256 blocks x 512 threads (2 waves/SIMD).
// xcd = bid&7; sub = bid>>3; m-tile grp = sub&3; j0 = (xcd*8+(sub>>2))*16.
// Waves = 8 k-eighths, 7-deep LDS reduce, wave-0 epilogue.
// Register-carried h (own tile) + Wx prefetch one step ahead.
// ---------------------------------------------------------------------------
__global__ __launch_bounds__(512, 1) void gru_layer(
    const unsigned short* __restrict__ Uhi, const unsigned short* __restrict__ Ulo,
    const float* __restrict__ Wx, const float* __restrict__ hinit,
    float* __restrict__ hRM, float* __restrict__ rhRM,
    float* __restrict__ hfin, int* cnt)
{
    extern __shared__ char smem[];
    unsigned short* hs_hi = (unsigned short*)smem;       // 16*LDK
    unsigned short* hs_lo = hs_hi + 16 * LDK;
    f32x4* red = (f32x4*)(hs_lo + 16 * LDK);             // 14*64 f32x4

    const int tid  = threadIdx.x;
    const int lane = tid & 63;
    const int kh   = __builtin_amdgcn_readfirstlane(tid >> 6);  // k-eighth 0..7
    const int la   = lane & 15;
    const int kg8  = (lane >> 4) * 8;
    const int erow = (lane >> 4) * 4;
    const int trow = tid >> 5;      // staging row 0..15
    const int tq   = tid & 31;      // staging f4 col group

    const int bid = blockIdx.x;
    const int xcd = bid & 7;
    const int sub = bid >> 3;
    const int grp = sub & 3;
    const int m0  = grp * 16;
    const int j0  = (xcd * 8 + (sub >> 2)) * 16;
    int* gcnt = cnt + grp * 8 * 32;

    const size_t HH = (size_t)H * H;
    const unsigned short* Ur_hi = Uhi;
    const unsigned short* Uz_hi = Uhi + HH;
    const unsigned short* Uh_hi = Uhi + 2 * HH;
    const unsigned short* Ur_lo = Ulo;
    const unsigned short* Uz_lo = Ulo + HH;
    const unsigned short* Uh_lo = Ulo + 2 * HH;

    int gen = 0;
    const int rbase = m0 + erow;

    // ---- wave-0 prologue: register-carried h + Wx[0] ----
    f32x4 zreg = (f32x4){0.f, 0.f, 0.f, 0.f};
    float hvC[4] = {0.f, 0.f, 0.f, 0.f};
    float wrC[4], wzC[4], whC[4];
    float wrN[4], wzN[4], whN[4];
    if (kh == 0) {
        #pragma unroll
        for (int qq = 0; qq < 4; ++qq) {
            hvC[qq] = hinit[(size_t)(rbase + qq) * H + j0 + la];
            const size_t wb = ((size_t)0 * B + rbase + qq) * (3 * H) + j0 + la;
            wrC[qq] = Wx[wb];
            wzC[qq] = Wx[wb + H];
            whC[qq] = Wx[wb + 2 * H];
        }
    }

    for (int t = 0; t < T; ++t) {
        const float* hprev = (t == 0) ? hinit : (hRM + (size_t)(t - 1) * B * H);

        // ================= phase A: r, z =================
        {
            // stage h m-tile (16 rows x 1024 fp32) -> LDS split hi/lo
            {
                const float* hrp = hprev + (size_t)(m0 + trow) * H;
                #pragma unroll
                for (int i = 0; i < 8; ++i) {
                    const int c = (tq + i * 32) * 4;
                    float4 v = *(const float4*)(hrp + c);
                    uint2 h2, l2;
                    splitpack(v, h2, l2);
                    *(uint2*)&hs_hi[trow * LDK + c] = h2;
                    *(uint2*)&hs_lo[trow * LDK + c] = l2;
                }
            }
            __syncthreads();
            f32x4 a0 = (f32x4){0.f, 0.f, 0.f, 0.f}, a1 = a0;
            const int kb = kh * 128 + kg8;
            #pragma unroll
            for (int ks = 0; ks < 4; ++ks) {
                const int ko = kb + ks * 32;
                const int ar = la * LDK + ko;
                bf16x8 ah = ld8(&hs_hi[ar]);
                bf16x8 al = ld8(&hs_lo[ar]);
                const size_t ub = (size_t)(j0 + la) * H + ko;
                a0 = mfma3(a0, ah, al, ld8(Ur_hi + ub), ld8(Ur_lo + ub));
                a1 = mfma3(a1, ah, al, ld8(Uz_hi + ub), ld8(Uz_lo + ub));
            }
            if (kh) {
                red[((kh - 1) * 2 + 0) * 64 + lane] = a0;
                red[((kh - 1) * 2 + 1) * 64 + lane] = a1;
            }
            __syncthreads();
            if (kh == 0) {
                #pragma unroll
                for (int w = 0; w < 7; ++w) {
                    a0 += red[(w * 2 + 0) * 64 + lane];
                    a1 += red[(w * 2 + 1) * 64 + lane];
                }
                #pragma unroll
                for (int qq = 0; qq < 4; ++qq) {
                    float rg = 1.f / (1.f + __expf(-(a0[qq] + wrC[qq])));
                    zreg[qq] = 1.f / (1.f + __expf(-(a1[qq] + wzC[qq])));
                    store_f32_sc(rhRM + ((size_t)t * B + rbase + qq) * H + j0 + la,
                                 rg * hvC[qq]);
                }
            }
        }
        gridbar_grp(gcnt, ++gen);

        // ================= phase B: h~ and update =================
        {
            // wave-0: prefetch next step's Wx (latency hides under staging+MFMA)
            if (kh == 0 && t + 1 < T) {
                #pragma unroll
                for (int qq = 0; qq < 4; ++qq) {
                    const size_t wb = ((size_t)(t + 1) * B + rbase + qq) * (3 * H) + j0 + la;
                    wrN[qq] = Wx[wb];
                    wzN[qq] = Wx[wb + H];
                    whN[qq] = Wx[wb + 2 * H];
                }
            }
            // stage rh m-tile
            {
                const float* rrp = rhRM + (size_t)t * B * H + (size_t)(m0 + trow) * H;
                #pragma unroll
                for (int i = 0; i < 8; ++i) {
                    const int c = (tq + i * 32) * 4;
                    float4 v = *(const float4*)(rrp + c);
                    uint2 h2, l2;
                    splitpack(v, h2, l2);
                    *(uint2*)&hs_hi[trow * LDK + c] = h2;
                    *(uint2*)&hs_lo[trow * LDK + c] = l2;
                }
            }
            __syncthreads();
            f32x4 a = (f32x4){0.f, 0.f, 0.f, 0.f};
            const int kb = kh * 128 + kg8;
            #pragma unroll
            for (int ks = 0; ks < 4; ++ks) {
                const int ko = kb + ks * 32;
                const int ar = la * LDK + ko;
                const size_t ub = (size_t)(j0 + la) * H + ko;
                a = mfma3(a, ld8(&hs_hi[ar]), ld8(&hs_lo[ar]),
                          ld8(Uh_hi + ub), ld8(Uh_lo + ub));
            }
            if (kh) red[(kh - 1) * 64 + lane] = a;
            __syncthreads();
            if (kh == 0) {
                #pragma unroll
                for (int w = 0; w < 7; ++w) a += red[w * 64 + lane];
                #pragma unroll
                for (int qq = 0; qq < 4; ++qq) {
                    float ht = tanhf(a[qq] + whC[qq]);
                    float hn = (1.f - zreg[qq]) * hvC[qq] + zreg[qq] * ht;
                    store_f32_sc(hRM + ((size_t)t * B + rbase + qq) * H + j0 + la, hn);
                    if (t == T - 1)
                        store_f32_sc(hfin + (size_t)(rbase + qq) * H + j0 + la, hn);
                    hvC[qq] = hn;
                    wrC[qq] = wrN[qq];
                    wzC[qq] = wzN[qq];
                    whC[qq] = whN[qq];
                }
            }
        }
        gridbar_grp(gcnt, ++gen);
    }
}

// ---------------------------------------------------------------------------
extern "C" void kernel_launch(void* const* d_in, const int* in_sizes, int n_in,
                              void* d_out, int out_size, void* d_ws, size_t ws_size,
                              hipStream_t stream)
{
    const int*   tok    = (const int*)d_in[0];
    const float* hidden = (const float*)d_in[1];
    const float* emb    = (const float*)d_in[2];
    const float* Wr0 = (const float*)d_in[3],  *br0 = (const float*)d_in[4];
    const float* Wz0 = (const float*)d_in[5],  *bz0 = (const float*)d_in[6];
    const float* Wh0 = (const float*)d_in[7],  *bh0 = (const float*)d_in[8];
    const float* Ur0 = (const float*)d_in[9],  *Uz0 = (const float*)d_in[10], *Uh0 = (const float*)d_in[11];
    const float* Wr1 = (const float*)d_in[12], *br1 = (const float*)d_in[13];
    const float* Wz1 = (const float*)d_in[14], *bz1 = (const float*)d_in[15];
    const float* Wh1 = (const float*)d_in[16], *bh1 = (const float*)d_in[17];
    const float* Ur1 = (const float*)d_in[18], *Uz1 = (const float*)d_in[19], *Uh1 = (const float*)d_in[20];
    const float* Wout = (const float*)d_in[21], *bout = (const float*)d_in[22];
    float* out = (float*)d_out;

    const size_t HH = (size_t)H * H;

    float* ws    = (float*)d_ws;
    float* Wx    = ws;                                   // T*B*3H (shared L0/L1)
    float* h0RM  = Wx    + (size_t)T * B * 3 * H;        // T*B*H
    float* rh0RM = h0RM  + (size_t)T * B * H;
    float* h1RM  = rh0RM + (size_t)T * B * H;
    float* rh1RM = h1RM  + (size_t)T * B * H;
    unsigned short* U0hi = (unsigned short*)(rh1RM + (size_t)T * B * H);
    unsigned short* U0lo = U0hi + 3 * HH;
    unsigned short* U1hi = U0lo + 3 * HH;
    unsigned short* U1lo = U1hi + 3 * HH;
    int* cnt0 = (int*)(U1lo + 3 * HH);                   // 4 grp * 8 stripes * 32
    int* cnt1 = cnt0 + 4 * 8 * 32;

    static bool attr_set = false;
    if (!attr_set) {
        (void)hipFuncSetAttribute((const void*)gru_layer,
                                  hipFuncAttributeMaxDynamicSharedMemorySize, 80384);
        attr_set = true;
    }

    (void)hipMemsetAsync(cnt0, 0, 2 * 4 * 8 * 32 * sizeof(int), stream);

    const int nHH = (int)(HH / 4);
    split_mat<<<nHH / 256, 256, 0, stream>>>(Ur0, U0hi + 0 * HH, U0lo + 0 * HH, nHH);
    split_mat<<<nHH / 256, 256, 0, stream>>>(Uz0, U0hi + 1 * HH, U0lo + 1 * HH, nHH);
    split_mat<<<nHH / 256, 256, 0, stream>>>(Uh0, U0hi + 2 * HH, U0lo + 2 * HH, nHH);
    split_mat<<<nHH / 256, 256, 0, stream>>>(Ur1, U1hi + 0 * HH, U1lo + 0 * HH, nHH);
    split_mat<<<nHH / 256, 256, 0, stream>>>(Uz1, U1hi + 1 * HH, U1lo + 1 * HH, nHH);
    split_mat<<<nHH / 256, 256, 0, stream>>>(Uh1, U1hi + 2 * HH, U1lo + 2 * HH, nHH);

    // ---- Wx(L0) = emb[tok] @ [Wr0;Wz0;Wh0]^T + b (gather fused, bias folded)
    gemm_mfma_split<<<dim3(H / 128, T * B / 128), 256, 0, stream>>>(emb, Wr0, br0, Wx, tok, T * B, H, E, E, E, 3 * H, 0);
    gemm_mfma_split<<<dim3(H / 128, T * B / 128), 256, 0, stream>>>(emb, Wz0, bz0, Wx, tok, T * B, H, E, E, E, 3 * H, H);
    gemm_mfma_split<<<dim3(H / 128, T * B / 128), 256, 0, stream>>>(emb, Wh0, bh0, Wx, tok, T * B, H, E, E, E, 3 * H, 2 * H);

    gru_layer<<<NWG, 512, 80384, stream>>>(U0hi, U0lo, Wx, hidden,
                                           h0RM, rh0RM, out + (size_t)T * B * V, cnt0);

    // ---- Wx(L1) = h0_seq @ [Wr1;Wz1;Wh1]^T + b
    gemm_mfma_split<<<dim3(H / 128, T * B / 128), 256, 0, stream>>>(h0RM, Wr1, br1, Wx, nullptr, T * B, H, H, H, H, 3 * H, 0);
    gemm_mfma_split<<<dim3(H / 128, T * B / 128), 256, 0, stream>>>(h0RM, Wz1, bz1, Wx, nullptr, T * B, H, H, H, H, 3 * H, H);
    gemm_mfma_split<<<dim3(H / 128, T * B / 128), 256, 0, stream>>>(h0RM, Wh1, bh1, Wx, nullptr, T * B, H, H, H, H, 3 * H, 2 * H);

    gru_layer<<<NWG, 512, 80384, stream>>>(U1hi, U1lo, Wx, hidden + (size_t)B * H,
                                           h1RM, rh1RM,
                                           out + (size_t)T * B * V + (size_t)B * H, cnt1);

    // ---- logits = h1_seq @ Wout^T + bout
    gemm_mfma_split<<<dim3((V + 127) / 128, T * B / 128), 256, 0, stream>>>(
        h1RM, Wout, bout, out, nullptr, T * B, V, H, H, H, V, 0);
}

// Round 13
// 3600.809 us; speedup vs baseline: 2.6019x; 1.1713x over previous
//
#include <hip/hip_runtime.h>
#include <hip/hip_bf16.h>
#include <math.h>

#define V 10000
#define E 512
#define H 1024
#define T 128
#define B 64
#define NWG 256
#define LDK 1032   // LDS row stride in ushorts (2064 B -> benign 2-lane/bank aliasing)

typedef __bf16 bf16x8 __attribute__((ext_vector_type(8)));
typedef float f32x4 __attribute__((ext_vector_type(4)));
typedef unsigned short ushort8 __attribute__((ext_vector_type(8)));

// ---------------------------------------------------------------------------
// Cache-bypassing (coherent-at-MALL) access helpers (validated R4-R12).
// ---------------------------------------------------------------------------
__device__ __forceinline__ void store_f32_sc(float* p, float v) {
    asm volatile("global_store_dword %0, %1, off sc0 sc1" :: "v"(p), "v"(v) : "memory");
}
__device__ __forceinline__ int load_i32_sc(const int* p) {
    int r;
    asm volatile("global_load_dword %0, %1, off sc0 sc1\n\ts_waitcnt vmcnt(0)"
                 : "=v"(r) : "v"(p) : "memory");
    return r;
}

// ---------------------------------------------------------------------------
// Per-m-tile-group grid barrier: 64 blocks/group, 8 stripes (one per XCD).
// ---------------------------------------------------------------------------
__device__ __forceinline__ void gridbar_grp(int* gcnt, int gen) {
    asm volatile("s_waitcnt vmcnt(0)" ::: "memory");
    __syncthreads();
    if (threadIdx.x == 0)
        __hip_atomic_fetch_add(gcnt + (blockIdx.x & 7) * 32, 1,
                               __ATOMIC_RELAXED, __HIP_MEMORY_SCOPE_AGENT);
    if (threadIdx.x < 8) {
        const int target = gen * 8;
        while (load_i32_sc(gcnt + threadIdx.x * 32) < target)
            __builtin_amdgcn_s_sleep(2);
    }
    __syncthreads();
}

// ---------------------------------------------------------------------------
// Split-pack 4 fp32 into truncated-hi bf16 and residual-lo bf16 (packed).
// ---------------------------------------------------------------------------
__device__ inline void splitpack(float4 v, uint2& hi, uint2& lo) {
    unsigned u0 = __float_as_uint(v.x), u1 = __float_as_uint(v.y);
    unsigned u2 = __float_as_uint(v.z), u3 = __float_as_uint(v.w);
    hi.x = __builtin_amdgcn_perm(u1, u0, 0x07060302u);
    hi.y = __builtin_amdgcn_perm(u3, u2, 0x07060302u);
    float l0 = v.x - __uint_as_float(u0 & 0xFFFF0000u);
    float l1 = v.y - __uint_as_float(u1 & 0xFFFF0000u);
    float l2 = v.z - __uint_as_float(u2 & 0xFFFF0000u);
    float l3 = v.w - __uint_as_float(u3 & 0xFFFF0000u);
    lo.x = __builtin_amdgcn_perm(__float_as_uint(l1), __float_as_uint(l0), 0x07060302u);
    lo.y = __builtin_amdgcn_perm(__float_as_uint(l3), __float_as_uint(l2), 0x07060302u);
}

__device__ __forceinline__ bf16x8 ld8(const unsigned short* p) {
    return __builtin_bit_cast(bf16x8, *(const ushort8*)p);
}
__device__ __forceinline__ f32x4 mfma3(f32x4 acc, bf16x8 ah, bf16x8 al,
                                       bf16x8 bh, bf16x8 bl) {
    acc = __builtin_amdgcn_mfma_f32_16x16x32_bf16(ah, bh, acc, 0, 0, 0);
    acc = __builtin_amdgcn_mfma_f32_16x16x32_bf16(al, bh, acc, 0, 0, 0);
    acc = __builtin_amdgcn_mfma_f32_16x16x32_bf16(ah, bl, acc, 0, 0, 0);
    return acc;
}

// ---------------------------------------------------------------------------
// Split-bf16 MFMA GEMM with optional row gather + column offset (proven).
// Used for the logits GEMM.
// ---------------------------------------------------------------------------
__global__ __launch_bounds__(256) void gemm_mfma_split(
    const float* __restrict__ A, const float* __restrict__ W,
    const float* __restrict__ bias, float* __restrict__ C,
    const int* __restrict__ rowidx,
    int M, int N, int K, int lda, int ldbw, int ldc, int coff)
{
    __shared__ __align__(16) unsigned short Ah[128 * 40];
    __shared__ __align__(16) unsigned short Al[128 * 40];
    __shared__ __align__(16) unsigned short Bh[128 * 40];
    __shared__ __align__(16) unsigned short Bl[128 * 40];

    const int tid  = threadIdx.x;
    const int lane = tid & 63;
    const int wv   = tid >> 6;
    const int wm   = wv & 1, wn = wv >> 1;
    const int bn = blockIdx.x * 128;
    const int bm = blockIdx.y * 128;

    const float* apt[4];
    const float* bpt[4];
    bool bok[4];
    unsigned lofs[4];
    #pragma unroll
    for (int i = 0; i < 4; ++i) {
        int f4 = i * 256 + tid, r = f4 >> 3, kq = f4 & 7;
        int gm = bm + r;
        int ar = rowidx ? rowidx[gm] : gm;
        apt[i] = A + (size_t)ar * lda + kq * 4;
        int gn = bn + r;
        bok[i] = (gn < N);
        bpt[i] = W + (size_t)(bok[i] ? gn : 0) * ldbw + kq * 4;
        lofs[i] = r * 40 + kq * 4;
    }

    f32x4 acc[4][4];
    #pragma unroll
    for (int i = 0; i < 4; ++i)
        #pragma unroll
        for (int j = 0; j < 4; ++j) acc[i][j] = (f32x4){0.f, 0.f, 0.f, 0.f};

    const int la  = lane & 15;
    const int kg8 = (lane >> 4) * 8;

    for (int k0 = 0; k0 < K; k0 += 32) {
        __syncthreads();
        #pragma unroll
        for (int i = 0; i < 4; ++i) {
            float4 va = *(const float4*)(apt[i] + k0);
            uint2 h, l;
            splitpack(va, h, l);
            *(uint2*)&Ah[lofs[i]] = h;
            *(uint2*)&Al[lofs[i]] = l;
            float4 vb = {0.f, 0.f, 0.f, 0.f};
            if (bok[i]) vb = *(const float4*)(bpt[i] + k0);
            splitpack(vb, h, l);
            *(uint2*)&Bh[lofs[i]] = h;
            *(uint2*)&Bl[lofs[i]] = l;
        }
        __syncthreads();

        bf16x8 ah[4], al[4];
        #pragma unroll
        for (int mt = 0; mt < 4; ++mt) {
            int row = (wm * 64 + mt * 16 + la) * 40 + kg8;
            ah[mt] = ld8(&Ah[row]);
            al[mt] = ld8(&Al[row]);
        }
        #pragma unroll
        for (int nt = 0; nt < 4; ++nt) {
            int row = (wn * 64 + nt * 16 + la) * 40 + kg8;
            bf16x8 bh = ld8(&Bh[row]);
            bf16x8 bl = ld8(&Bl[row]);
            #pragma unroll
            for (int mt = 0; mt < 4; ++mt)
                acc[mt][nt] = mfma3(acc[mt][nt], ah[mt], al[mt], bh, bl);
        }
    }

    #pragma unroll
    for (int mt = 0; mt < 4; ++mt) {
        int mrow = bm + wm * 64 + mt * 16 + (lane >> 4) * 4;
        #pragma unroll
        for (int nt = 0; nt < 4; ++nt) {
            int n = bn + wn * 64 + nt * 16 + la;
            if (n < N) {
                float bi = bias ? bias[n] : 0.f;
                #pragma unroll
                for (int r = 0; r < 4; ++r)
                    C[(size_t)(mrow + r) * ldc + n + coff] = acc[mt][nt][r] + bi;
            }
        }
    }
}

// ---------------------------------------------------------------------------
// Batched 3-gate Wx GEMM: gridDim.z = 3 selects (W, bias); coff = z*H.
// N = H exactly (no bounds checks). C layout [M][3H].
// ---------------------------------------------------------------------------
__global__ __launch_bounds__(256) void gemm_wx3(
    const float* __restrict__ A,
    const float* __restrict__ W0, const float* __restrict__ W1, const float* __restrict__ W2,
    const float* __restrict__ b0, const float* __restrict__ b1, const float* __restrict__ b2,
    float* __restrict__ C, const int* __restrict__ rowidx,
    int K, int lda)
{
    __shared__ __align__(16) unsigned short Ah[128 * 40];
    __shared__ __align__(16) unsigned short Al[128 * 40];
    __shared__ __align__(16) unsigned short Bh[128 * 40];
    __shared__ __align__(16) unsigned short Bl[128 * 40];

    const int z = blockIdx.z;
    const float* __restrict__ W    = (z == 0) ? W0 : (z == 1) ? W1 : W2;
    const float* __restrict__ bias = (z == 0) ? b0 : (z == 1) ? b1 : b2;
    const int coff = z * H;

    const int tid  = threadIdx.x;
    const int lane = tid & 63;
    const int wv   = tid >> 6;
    const int wm   = wv & 1, wn = wv >> 1;
    const int bn = blockIdx.x * 128;
    const int bm = blockIdx.y * 128;

    const float* apt[4];
    const float* bpt[4];
    unsigned lofs[4];
    #pragma unroll
    for (int i = 0; i < 4; ++i) {
        int f4 = i * 256 + tid, r = f4 >> 3, kq = f4 & 7;
        int gm = bm + r;
        int ar = rowidx ? rowidx[gm] : gm;
        apt[i] = A + (size_t)ar * lda + kq * 4;
        bpt[i] = W + (size_t)(bn + r) * K + kq * 4;
        lofs[i] = r * 40 + kq * 4;
    }

    f32x4 acc[4][4];
    #pragma unroll
    for (int i = 0; i < 4; ++i)
        #pragma unroll
        for (int j = 0; j < 4; ++j) acc[i][j] = (f32x4){0.f, 0.f, 0.f, 0.f};

    const int la  = lane & 15;
    const int kg8 = (lane >> 4) * 8;

    for (int k0 = 0; k0 < K; k0 += 32) {
        __syncthreads();
        #pragma unroll
        for (int i = 0; i < 4; ++i) {
            float4 va = *(const float4*)(apt[i] + k0);
            uint2 h, l;
            splitpack(va, h, l);
            *(uint2*)&Ah[lofs[i]] = h;
            *(uint2*)&Al[lofs[i]] = l;
            float4 vb = *(const float4*)(bpt[i] + k0);
            splitpack(vb, h, l);
            *(uint2*)&Bh[lofs[i]] = h;
            *(uint2*)&Bl[lofs[i]] = l;
        }
        __syncthreads();

        bf16x8 ah[4], al[4];
        #pragma unroll
        for (int mt = 0; mt < 4; ++mt) {
            int row = (wm * 64 + mt * 16 + la) * 40 + kg8;
            ah[mt] = ld8(&Ah[row]);
            al[mt] = ld8(&Al[row]);
        }
        #pragma unroll
        for (int nt = 0; nt < 4; ++nt) {
            int row = (wn * 64 + nt * 16 + la) * 40 + kg8;
            bf16x8 bh = ld8(&Bh[row]);
            bf16x8 bl = ld8(&Bl[row]);
            #pragma unroll
            for (int mt = 0; mt < 4; ++mt)
                acc[mt][nt] = mfma3(acc[mt][nt], ah[mt], al[mt], bh, bl);
        }
    }

    #pragma unroll
    for (int mt = 0; mt < 4; ++mt) {
        int mrow = bm + wm * 64 + mt * 16 + (lane >> 4) * 4;
        #pragma unroll
        for (int nt = 0; nt < 4; ++nt) {
            int n = bn + wn * 64 + nt * 16 + la;
            float bi = bias[n];
            #pragma unroll
            for (int r = 0; r < 4; ++r)
                C[(size_t)(mrow + r) * (3 * H) + n + coff] = acc[mt][nt][r] + bi;
        }
    }
}

// ---------------------------------------------------------------------------
// Prepass: split one fp32 matrix into bf16 hi/lo.
// ---------------------------------------------------------------------------
__global__ __launch_bounds__(256) void split_mat(
    const float* __restrict__ U, unsigned short* __restrict__ hi,
    unsigned short* __restrict__ lo, int nf4)
{
    int idx = blockIdx.x * 256 + threadIdx.x;
    if (idx >= nf4) return;
    float4 v = ((const float4*)U)[idx];
    uint2 h, l;
    splitpack(v, h, l);
    ((uint2*)hi)[idx] = h;
    ((uint2*)lo)[idx] = l;
}

// ---------------------------------------------------------------------------
// Persistent single-layer GRU. XCD-resident U; 4 independent 64-block m-tile
// groups. 256 blocks x 1024 threads (16 waves = 4/SIMD, 50% occupancy).
// Waves = 16 k-sixteenths (64-wide), 15-deep LDS reduce, wave-0 epilogue.
// Register-carried h + one-step Wx prefetch (R12-proven).
// ---------------------------------------------------------------------------
__global__ __launch_bounds__(1024, 1) void gru_layer(
    const unsigned short* __restrict__ Uhi, const unsigned short* __restrict__ Ulo,
    const float* __restrict__ Wx, const float* __restrict__ hinit,
    float* __restrict__ hRM, float* __restrict__ rhRM,
    float* __restrict__ hfin, int* cnt)
{
    extern __shared__ char smem[];
    unsigned short* hs_hi = (unsigned short*)smem;       // 16*LDK
    unsigned short* hs_lo = hs_hi + 16 * LDK;
    f32x4* red = (f32x4*)(hs_lo + 16 * LDK);             // 30*64 f32x4

    const int tid  = threadIdx.x;
    const int lane = tid & 63;
    const int kh   = __builtin_amdgcn_readfirstlane(tid >> 6);  // k-16th 0..15
    const int la   = lane & 15;
    const int kg8  = (lane >> 4) * 8;
    const int erow = (lane >> 4) * 4;
    const int trow = tid >> 6;      // staging row 0..15
    const int tq   = tid & 63;      // staging f4 col group

    const int bid = blockIdx.x;
    const int xcd = bid & 7;
    const int sub = bid >> 3;
    const int grp = sub & 3;
    const int m0  = grp * 16;
    const int j0  = (xcd * 8 + (sub >> 2)) * 16;
    int* gcnt = cnt + grp * 8 * 32;

    const size_t HH = (size_t)H * H;
    const unsigned short* Ur_hi = Uhi;
    const unsigned short* Uz_hi = Uhi + HH;
    const unsigned short* Uh_hi = Uhi + 2 * HH;
    const unsigned short* Ur_lo = Ulo;
    const unsigned short* Uz_lo = Ulo + HH;
    const unsigned short* Uh_lo = Ulo + 2 * HH;

    int gen = 0;
    const int rbase = m0 + erow;

    // ---- wave-0 prologue: register-carried h + Wx[0] ----
    f32x4 zreg = (f32x4){0.f, 0.f, 0.f, 0.f};
    float hvC[4] = {0.f, 0.f, 0.f, 0.f};
    float wrC[4], wzC[4], whC[4];
    float wrN[4], wzN[4], whN[4];
    if (kh == 0) {
        #pragma unroll
        for (int qq = 0; qq < 4; ++qq) {
            hvC[qq] = hinit[(size_t)(rbase + qq) * H + j0 + la];
            const size_t wb = ((size_t)0 * B + rbase + qq) * (3 * H) + j0 + la;
            wrC[qq] = Wx[wb];
            wzC[qq] = Wx[wb + H];
            whC[qq] = Wx[wb + 2 * H];
        }
    }

    for (int t = 0; t < T; ++t) {
        const float* hprev = (t == 0) ? hinit : (hRM + (size_t)(t - 1) * B * H);

        // ================= phase A: r, z =================
        {
            // stage h m-tile (16 rows x 1024 fp32) -> LDS split hi/lo
            {
                const float* hrp = hprev + (size_t)(m0 + trow) * H;
                #pragma unroll
                for (int i = 0; i < 4; ++i) {
                    const int c = (tq + i * 64) * 4;
                    float4 v = *(const float4*)(hrp + c);
                    uint2 h2, l2;
                    splitpack(v, h2, l2);
                    *(uint2*)&hs_hi[trow * LDK + c] = h2;
                    *(uint2*)&hs_lo[trow * LDK + c] = l2;
                }
            }
            __syncthreads();
            f32x4 a0 = (f32x4){0.f, 0.f, 0.f, 0.f}, a1 = a0;
            const int kb = kh * 64 + kg8;
            #pragma unroll
            for (int ks = 0; ks < 2; ++ks) {
                const int ko = kb + ks * 32;
                const int ar = la * LDK + ko;
                bf16x8 ah = ld8(&hs_hi[ar]);
                bf16x8 al = ld8(&hs_lo[ar]);
                const size_t ub = (size_t)(j0 + la) * H + ko;
                a0 = mfma3(a0, ah, al, ld8(Ur_hi + ub), ld8(Ur_lo + ub));
                a1 = mfma3(a1, ah, al, ld8(Uz_hi + ub), ld8(Uz_lo + ub));
            }
            if (kh) {
                red[((kh - 1) * 2 + 0) * 64 + lane] = a0;
                red[((kh - 1) * 2 + 1) * 64 + lane] = a1;
            }
            __syncthreads();
            if (kh == 0) {
                #pragma unroll
                for (int w = 0; w < 15; ++w) {
                    a0 += red[(w * 2 + 0) * 64 + lane];
                    a1 += red[(w * 2 + 1) * 64 + lane];
                }
                #pragma unroll
                for (int qq = 0; qq < 4; ++qq) {
                    float rg = 1.f / (1.f + __expf(-(a0[qq] + wrC[qq])));
                    zreg[qq] = 1.f / (1.f + __expf(-(a1[qq] + wzC[qq])));
                    store_f32_sc(rhRM + ((size_t)t * B + rbase + qq) * H + j0 + la,
                                 rg * hvC[qq]);
                }
            }
        }
        gridbar_grp(gcnt, ++gen);

        // ================= phase B: h~ and update =================
        {
            // wave-0: prefetch next step's Wx (hides under staging+MFMA)
            if (kh == 0 && t + 1 < T) {
                #pragma unroll
                for (int qq = 0; qq < 4; ++qq) {
                    const size_t wb = ((size_t)(t + 1) * B + rbase + qq) * (3 * H) + j0 + la;
                    wrN[qq] = Wx[wb];
                    wzN[qq] = Wx[wb + H];
                    whN[qq] = Wx[wb + 2 * H];
                }
            }
            // stage rh m-tile
            {
                const float* rrp = rhRM + (size_t)t * B * H + (size_t)(m0 + trow) * H;
                #pragma unroll
                for (int i = 0; i < 4; ++i) {
                    const int c = (tq + i * 64) * 4;
                    float4 v = *(const float4*)(rrp + c);
                    uint2 h2, l2;
                    splitpack(v, h2, l2);
                    *(uint2*)&hs_hi[trow * LDK + c] = h2;
                    *(uint2*)&hs_lo[trow * LDK + c] = l2;
                }
            }
            __syncthreads();
            f32x4 a = (f32x4){0.f, 0.f, 0.f, 0.f};
            const int kb = kh * 64 + kg8;
            #pragma unroll
            for (int ks = 0; ks < 2; ++ks) {
                const int ko = kb + ks * 32;
                const int ar = la * LDK + ko;
                const size_t ub = (size_t)(j0 + la) * H + ko;
                a = mfma3(a, ld8(&hs_hi[ar]), ld8(&hs_lo[ar]),
                          ld8(Uh_hi + ub), ld8(Uh_lo + ub));
            }
            if (kh) red[(kh - 1) * 64 + lane] = a;
            __syncthreads();
            if (kh == 0) {
                #pragma unroll
                for (int w = 0; w < 15; ++w) a += red[w * 64 + lane];
                #pragma unroll
                for (int qq = 0; qq < 4; ++qq) {
                    float ht = tanhf(a[qq] + whC[qq]);
                    float hn = (1.f - zreg[qq]) * hvC[qq] + zreg[qq] * ht;
                    store_f32_sc(hRM + ((size_t)t * B + rbase + qq) * H + j0 + la, hn);
                    if (t == T - 1)
                        store_f32_sc(hfin + (size_t)(rbase + qq) * H + j0 + la, hn);
                    hvC[qq] = hn;
                    wrC[qq] = wrN[qq];
                    wzC[qq] = wzN[qq];
                    whC[qq] = whN[qq];
                }
            }
        }
        gridbar_grp(gcnt, ++gen);
    }
}

// ---------------------------------------------------------------------------
extern "C" void kernel_launch(void* const* d_in, const int* in_sizes, int n_in,
                              void* d_out, int out_size, void* d_ws, size_t ws_size,
                              hipStream_t stream)
{
    const int*   tok    = (const int*)d_in[0];
    const float* hidden = (const float*)d_in[1];
    const float* emb    = (const float*)d_in[2];
    const float* Wr0 = (const float*)d_in[3],  *br0 = (const float*)d_in[4];
    const float* Wz0 = (const float*)d_in[5],  *bz0 = (const float*)d_in[6];
    const float* Wh0 = (const float*)d_in[7],  *bh0 = (const float*)d_in[8];
    const float* Ur0 = (const float*)d_in[9],  *Uz0 = (const float*)d_in[10], *Uh0 = (const float*)d_in[11];
    const float* Wr1 = (const float*)d_in[12], *br1 = (const float*)d_in[13];
    const float* Wz1 = (const float*)d_in[14], *bz1 = (const float*)d_in[15];
    const float* Wh1 = (const float*)d_in[16], *bh1 = (const float*)d_in[17];
    const float* Ur1 = (const float*)d_in[18], *Uz1 = (const float*)d_in[19], *Uh1 = (const float*)d_in[20];
    const float* Wout = (const float*)d_in[21], *bout = (const float*)d_in[22];
    float* out = (float*)d_out;

    const size_t HH = (size_t)H * H;

    float* ws    = (float*)d_ws;
    float* Wx    = ws;                                   // T*B*3H (shared L0/L1)
    float* h0RM  = Wx    + (size_t)T * B * 3 * H;        // T*B*H
    float* rh0RM = h0RM  + (size_t)T * B * H;
    float* h1RM  = rh0RM + (size_t)T * B * H;
    float* rh1RM = h1RM  + (size_t)T * B * H;
    unsigned short* U0hi = (unsigned short*)(rh1RM + (size_t)T * B * H);
    unsigned short* U0lo = U0hi + 3 * HH;
    unsigned short* U1hi = U0lo + 3 * HH;
    unsigned short* U1lo = U1hi + 3 * HH;
    int* cnt0 = (int*)(U1lo + 3 * HH);                   // 4 grp * 8 stripes * 32
    int* cnt1 = cnt0 + 4 * 8 * 32;

    static bool attr_set = false;
    if (!attr_set) {
        (void)hipFuncSetAttribute((const void*)gru_layer,
                                  hipFuncAttributeMaxDynamicSharedMemorySize, 96768);
        attr_set = true;
    }

    (void)hipMemsetAsync(cnt0, 0, 2 * 4 * 8 * 32 * sizeof(int), stream);

    const int nHH = (int)(HH / 4);
    split_mat<<<nHH / 256, 256, 0, stream>>>(Ur0, U0hi + 0 * HH, U0lo + 0 * HH, nHH);
    split_mat<<<nHH / 256, 256, 0, stream>>>(Uz0, U0hi + 1 * HH, U0lo + 1 * HH, nHH);
    split_mat<<<nHH / 256, 256, 0, stream>>>(Uh0, U0hi + 2 * HH, U0lo + 2 * HH, nHH);
    split_mat<<<nHH / 256, 256, 0, stream>>>(Ur1, U1hi + 0 * HH, U1lo + 0 * HH, nHH);
    split_mat<<<nHH / 256, 256, 0, stream>>>(Uz1, U1hi + 1 * HH, U1lo + 1 * HH, nHH);
    split_mat<<<nHH / 256, 256, 0, stream>>>(Uh1, U1hi + 2 * HH, U1lo + 2 * HH, nHH);

    // ---- Wx(L0) = emb[tok] @ [Wr0;Wz0;Wh0]^T + b (one batched launch)
    gemm_wx3<<<dim3(H / 128, T * B / 128, 3), 256, 0, stream>>>(
        emb, Wr0, Wz0, Wh0, br0, bz0, bh0, Wx, tok, E, E);

    gru_layer<<<NWG, 1024, 96768, stream>>>(U0hi, U0lo, Wx, hidden,
                                            h0RM, rh0RM, out + (size_t)T * B * V, cnt0);

    // ---- Wx(L1) = h0_seq @ [Wr1;Wz1;Wh1]^T + b (one batched launch)
    gemm_wx3<<<dim3(H / 128, T * B / 128, 3), 256, 0, stream>>>(
        h0RM, Wr1, Wz1, Wh1, br1, bz1, bh1, Wx, nullptr, H, H);

    gru_layer<<<NWG, 1024, 96768, stream>>>(U1hi, U1lo, Wx, hidden + (size_t)B * H,
                                            h1RM, rh1RM,
                                            out + (size_t)T * B * V + (size_t)B * H, cnt1);

    // ---- logits = h1_seq @ Wout^T + bout
    gemm_mfma_split<<<dim3((V + 127) / 128, T * B / 128), 256, 0, stream>>>(
        h1RM, Wout, bout, out, nullptr, T * B, V, H, H, H, V, 0);
}